// Round 1
// baseline (600.662 us; speedup 1.0000x reference)
//
#include <hip/hip_runtime.h>
#include <hip/hip_bf16.h>

#define NN 100000
#define NE 1600000
#define E2 (NE + NN)          // edges + self loops
#define NEG_SLOPE 0.2f
#define GEPS 1e-16f

// ---------- tiny prep: q1[3][2] (layer1 edge-att vector), q2[3] (layer2) ----------
__global__ void k_prep(const float* __restrict__ We1, const float* __restrict__ ae1,
                       const float* __restrict__ We2, const float* __restrict__ ae2,
                       float* __restrict__ q) {
  int t = threadIdx.x;
  if (t < 6) {                       // q[d*2+hh] = sum_c We1[d, hh*64+c] * ae1[hh*64+c]
    int d = t >> 1, hh = t & 1;
    float s = 0.f;
    for (int c = 0; c < 64; ++c) s += We1[d * 128 + hh * 64 + c] * ae1[hh * 64 + c];
    q[t] = s;
  } else if (t < 9) {                // q[8+d] = sum_j We2[d,j]*ae2[j]
    int d = t - 6;
    q[8 + d] = We2[d * 2 + 0] * ae2[0] + We2[d * 2 + 1] * ae2[1];
  }
}

// ---------- layer1 GEMM: h1[N,128] = x[N,128] @ W1[128,128] ----------
// W1 staged fully in LDS (64KB). Block = 256 thr, 32 rows x 128 cols per block,
// thread tile 4x4. x read straight from global (row-uniform across 32 lanes -> L1 broadcast).
__global__ __launch_bounds__(256) void k_gemm(const float* __restrict__ x,
                                              const float* __restrict__ W,
                                              float* __restrict__ h1) {
  __shared__ float ws[128 * 128];
  int t = threadIdx.x;
  for (int i = t * 4; i < 128 * 128; i += 1024)
    *(float4*)&ws[i] = *(const float4*)&W[i];
  __syncthreads();
  int row0 = blockIdx.x * 32;
  int tc = t & 31, tr = t >> 5;
  int c0 = tc * 4;
  int r0 = row0 + tr * 4;
  float acc[4][4];
#pragma unroll
  for (int r = 0; r < 4; ++r)
#pragma unroll
    for (int c = 0; c < 4; ++c) acc[r][c] = 0.f;

  for (int kk = 0; kk < 128; kk += 4) {
    float4 wv[4], xv[4];
#pragma unroll
    for (int j = 0; j < 4; ++j) wv[j] = *(const float4*)&ws[(kk + j) * 128 + c0];
#pragma unroll
    for (int r = 0; r < 4; ++r) xv[r] = *(const float4*)&x[(size_t)(r0 + r) * 128 + kk];
#pragma unroll
    for (int r = 0; r < 4; ++r) {
      acc[r][0] += xv[r].x * wv[0].x + xv[r].y * wv[1].x + xv[r].z * wv[2].x + xv[r].w * wv[3].x;
      acc[r][1] += xv[r].x * wv[0].y + xv[r].y * wv[1].y + xv[r].z * wv[2].y + xv[r].w * wv[3].y;
      acc[r][2] += xv[r].x * wv[0].z + xv[r].y * wv[1].z + xv[r].z * wv[2].z + xv[r].w * wv[3].z;
      acc[r][3] += xv[r].x * wv[0].w + xv[r].y * wv[1].w + xv[r].z * wv[2].w + xv[r].w * wv[3].w;
    }
  }
#pragma unroll
  for (int r = 0; r < 4; ++r) {
    float4 v = make_float4(acc[r][0], acc[r][1], acc[r][2], acc[r][3]);
    *(float4*)&h1[(size_t)(r0 + r) * 128 + c0] = v;
  }
}

// ---------- per-node attention scalars: a1s[n,h], a1d[n,h] ----------
__global__ __launch_bounds__(256) void k_attn1(const float* __restrict__ h1,
                                               const float* __restrict__ as1,
                                               const float* __restrict__ ad1,
                                               float* __restrict__ a1s, float* __restrict__ a1d) {
  int wid = (int)((blockIdx.x * 256 + threadIdx.x) >> 6);
  int lane = threadIdx.x & 63;
  if (wid >= NN) return;
  float h0 = h1[(size_t)wid * 128 + lane];
  float hA = h1[(size_t)wid * 128 + 64 + lane];
  float s0 = h0 * as1[lane], s1 = hA * as1[64 + lane];
  float d0 = h0 * ad1[lane], d1 = hA * ad1[64 + lane];
  for (int o = 32; o > 0; o >>= 1) {
    s0 += __shfl_xor(s0, o); s1 += __shfl_xor(s1, o);
    d0 += __shfl_xor(d0, o); d1 += __shfl_xor(d1, o);
  }
  if (lane == 0) {
    a1s[wid * 2] = s0; a1s[wid * 2 + 1] = s1;
    a1d[wid * 2] = d0; a1d[wid * 2 + 1] = d1;
  }
}

// ---------- CSR build ----------
__global__ void k_hist(const int* __restrict__ ei, int* __restrict__ deg) {
  int e = blockIdx.x * 256 + threadIdx.x;
  if (e >= E2) return;
  int dst = (e < NE) ? ei[NE + e] : (e - NE);
  atomicAdd(&deg[dst], 1);
}

__global__ void k_scan1(const int* __restrict__ deg, int* __restrict__ bsum) {
  __shared__ int lds[256];
  int t = threadIdx.x;
  int base = blockIdx.x * 1024 + t * 4;
  int s = 0;
  for (int j = 0; j < 4; ++j) { int i = base + j; s += (i < NN) ? deg[i] : 0; }
  lds[t] = s; __syncthreads();
  for (int o = 128; o > 0; o >>= 1) { if (t < o) lds[t] += lds[t + o]; __syncthreads(); }
  if (t == 0) bsum[blockIdx.x] = lds[0];
}

__global__ void k_scan2(int* __restrict__ bsum, int nb) {
  __shared__ int lds[128];
  int t = threadIdx.x;
  int v = (t < nb) ? bsum[t] : 0;
  lds[t] = v; __syncthreads();
  for (int o = 1; o < 128; o <<= 1) {
    int u = (t >= o) ? lds[t - o] : 0;
    __syncthreads();
    lds[t] += u;
    __syncthreads();
  }
  if (t < nb) bsum[t] = lds[t] - v;   // exclusive
}

__global__ void k_scan3(const int* __restrict__ deg, const int* __restrict__ bbase,
                        int* __restrict__ rowptr, int* __restrict__ cursor) {
  __shared__ int lds[256];
  int t = threadIdx.x;
  int base = blockIdx.x * 1024 + t * 4;
  int v[4]; int s = 0;
  for (int j = 0; j < 4; ++j) { int i = base + j; v[j] = (i < NN) ? deg[i] : 0; s += v[j]; }
  lds[t] = s; __syncthreads();
  for (int o = 1; o < 256; o <<= 1) {
    int u = (t >= o) ? lds[t - o] : 0;
    __syncthreads();
    lds[t] += u;
    __syncthreads();
  }
  int excl = lds[t] - s + bbase[blockIdx.x];
  for (int j = 0; j < 4; ++j) {
    int i = base + j;
    if (i <= NN) {
      rowptr[i] = excl;
      if (i < NN) cursor[i] = excl;
    }
    excl += v[j];
  }
}

// ---------- scatter edges into CSR, packing (alpha0, alpha1, src, ae2) per slot ----------
__global__ void k_scatter(const int* __restrict__ ei, const float* __restrict__ ef,
                          const float* __restrict__ a1s, const float* __restrict__ a1d,
                          const float* __restrict__ q, int* __restrict__ cursor,
                          float4* __restrict__ cpk) {
  int e = blockIdx.x * 256 + threadIdx.x;
  if (e >= E2) return;
  int src, dst; float e0, e1, ez;
  if (e < NE) {
    src = ei[e]; dst = ei[NE + e];
    float f0 = ef[(size_t)e * 3], f1 = ef[(size_t)e * 3 + 1], f2 = ef[(size_t)e * 3 + 2];
    e0 = f0 * q[0] + f1 * q[2] + f2 * q[4];
    e1 = f0 * q[1] + f1 * q[3] + f2 * q[5];
    ez = f0 * q[8] + f1 * q[9] + f2 * q[10];
  } else {
    src = dst = e - NE; e0 = e1 = ez = 0.f;   // self-loop, zero edge_attr
  }
  float al0 = a1s[src * 2] + a1d[dst * 2] + e0;
  float al1 = a1s[src * 2 + 1] + a1d[dst * 2 + 1] + e1;
  al0 = al0 > 0.f ? al0 : NEG_SLOPE * al0;
  al1 = al1 > 0.f ? al1 : NEG_SLOPE * al1;
  int pos = atomicAdd(&cursor[dst], 1);
  float4 pk;
  pk.x = al0; pk.y = al1; pk.z = __int_as_float(src); pk.w = ez;
  cpk[pos] = pk;
}

// ---------- layer1 aggregation + bias + ELU + layer2 projection epilogue ----------
// one wave per dst node; lane owns channel (lane) of head0 and (64+lane) of head1
__global__ __launch_bounds__(256) void k_agg1(const float* __restrict__ h1,
                                              const int* __restrict__ rowptr,
                                              const float4* __restrict__ cpk,
                                              const float* __restrict__ b1,
                                              const float* __restrict__ W2,
                                              const float* __restrict__ as2,
                                              const float* __restrict__ ad2,
                                              float* __restrict__ h2,
                                              float* __restrict__ a2s, float* __restrict__ a2d) {
  int n = (int)((blockIdx.x * 256 + threadIdx.x) >> 6);
  int lane = threadIdx.x & 63;
  if (n >= NN) return;
  int s0 = rowptr[n], s1 = rowptr[n + 1];
  // pass 1: segment max (lane-parallel over edges)
  float m0 = -1e30f, m1 = -1e30f;
  for (int i = s0 + lane; i < s1; i += 64) {
    float4 pk = cpk[i];
    m0 = fmaxf(m0, pk.x); m1 = fmaxf(m1, pk.y);
  }
  for (int o = 32; o > 0; o >>= 1) {
    m0 = fmaxf(m0, __shfl_xor(m0, o));
    m1 = fmaxf(m1, __shfl_xor(m1, o));
  }
  // pass 2: accumulate (edge-serial, wave-uniform; 512B coalesced row gathers)
  float acc0 = 0.f, acc1 = 0.f, d0 = 0.f, d1 = 0.f;
  for (int i = s0; i < s1; ++i) {
    float4 pk = cpk[i];
    int s = __float_as_int(pk.z);
    float p0 = __expf(pk.x - m0), p1 = __expf(pk.y - m1);
    d0 += p0; d1 += p1;
    acc0 += p0 * h1[(size_t)s * 128 + lane];
    acc1 += p1 * h1[(size_t)s * 128 + 64 + lane];
  }
  float r0 = acc0 / (d0 + GEPS) + b1[lane];
  float r1 = acc1 / (d1 + GEPS) + b1[64 + lane];
  r0 = r0 > 0.f ? r0 : __expf(r0) - 1.f;   // ELU
  r1 = r1 > 0.f ? r1 : __expf(r1) - 1.f;
  // layer2 projection: h2[n,j] = sum_c elu_out[c] * W2[c,j]
  float p20 = r0 * W2[lane * 2 + 0] + r1 * W2[(64 + lane) * 2 + 0];
  float p21 = r0 * W2[lane * 2 + 1] + r1 * W2[(64 + lane) * 2 + 1];
  for (int o = 32; o > 0; o >>= 1) { p20 += __shfl_xor(p20, o); p21 += __shfl_xor(p21, o); }
  if (lane == 0) {
    h2[n * 2] = p20; h2[n * 2 + 1] = p21;
    a2s[n] = p20 * as2[0] + p21 * as2[1];
    a2d[n] = p20 * ad2[0] + p21 * ad2[1];
  }
}

// ---------- layer2 aggregation (lane-parallel; tiny channels) ----------
__global__ __launch_bounds__(256) void k_agg2(const int* __restrict__ rowptr,
                                              const float4* __restrict__ cpk,
                                              const float* __restrict__ h2,
                                              const float* __restrict__ a2s,
                                              const float* __restrict__ a2d,
                                              const float* __restrict__ b2,
                                              float* __restrict__ out) {
  int n = (int)((blockIdx.x * 256 + threadIdx.x) >> 6);
  int lane = threadIdx.x & 63;
  if (n >= NN) return;
  int s0 = rowptr[n], s1 = rowptr[n + 1];
  float adn = a2d[n];
  float m = -1e30f;
  for (int i = s0 + lane; i < s1; i += 64) {
    float4 pk = cpk[i];
    int s = __float_as_int(pk.z);
    float v = a2s[s] + adn + pk.w;
    v = v > 0.f ? v : NEG_SLOPE * v;
    m = fmaxf(m, v);
  }
  for (int o = 32; o > 0; o >>= 1) m = fmaxf(m, __shfl_xor(m, o));
  float den = 0.f, acc0 = 0.f, acc1 = 0.f;
  for (int i = s0 + lane; i < s1; i += 64) {
    float4 pk = cpk[i];
    int s = __float_as_int(pk.z);
    float v = a2s[s] + adn + pk.w;
    v = v > 0.f ? v : NEG_SLOPE * v;
    float p = __expf(v - m);
    den += p;
    acc0 += p * h2[s * 2];
    acc1 += p * h2[s * 2 + 1];
  }
  for (int o = 32; o > 0; o >>= 1) {
    den += __shfl_xor(den, o);
    acc0 += __shfl_xor(acc0, o);
    acc1 += __shfl_xor(acc1, o);
  }
  if (lane == 0) {
    out[n * 2] = acc0 / (den + GEPS) + b2[0];
    out[n * 2 + 1] = acc1 / (den + GEPS) + b2[1];
  }
}

extern "C" void kernel_launch(void* const* d_in, const int* in_sizes, int n_in,
                              void* d_out, int out_size, void* d_ws, size_t ws_size,
                              hipStream_t stream) {
  (void)in_sizes; (void)n_in; (void)out_size; (void)ws_size;
  const float* x   = (const float*)d_in[0];
  const int*   ei  = (const int*)d_in[1];
  const float* ef  = (const float*)d_in[2];
  const float* W1  = (const float*)d_in[3];
  const float* We1 = (const float*)d_in[4];
  const float* as1 = (const float*)d_in[5];
  const float* ad1 = (const float*)d_in[6];
  const float* ae1 = (const float*)d_in[7];
  const float* b1  = (const float*)d_in[8];
  const float* W2  = (const float*)d_in[9];
  const float* We2 = (const float*)d_in[10];
  const float* as2 = (const float*)d_in[11];
  const float* ad2 = (const float*)d_in[12];
  const float* ae2 = (const float*)d_in[13];
  const float* b2  = (const float*)d_in[14];
  float* out = (float*)d_out;

  char* w = (char*)d_ws;
  auto alloc = [&](size_t bytes) -> char* {
    char* p = w; w += (bytes + 255) & ~(size_t)255; return p;
  };
  float*  h1     = (float*)alloc((size_t)NN * 128 * 4);   // 51.2 MB
  float*  a1s    = (float*)alloc((size_t)NN * 2 * 4);
  float*  a1d    = (float*)alloc((size_t)NN * 2 * 4);
  float*  h2     = (float*)alloc((size_t)NN * 2 * 4);
  float*  a2s    = (float*)alloc((size_t)NN * 4);
  float*  a2d    = (float*)alloc((size_t)NN * 4);
  float*  q      = (float*)alloc(64);
  int*    deg    = (int*)alloc((size_t)NN * 4);
  int*    rowptr = (int*)alloc((size_t)(NN + 1) * 4);
  int*    cursor = (int*)alloc((size_t)NN * 4);
  int*    bsum   = (int*)alloc(128 * 4);
  float4* cpk    = (float4*)alloc((size_t)E2 * 16);       // 27.2 MB

  const int NB_SCAN = (NN + 1023) / 1024;                 // 98

  hipLaunchKernelGGL(k_prep, dim3(1), dim3(16), 0, stream, We1, ae1, We2, ae2, q);
  hipLaunchKernelGGL(k_gemm, dim3(NN / 32), dim3(256), 0, stream, x, W1, h1);
  hipLaunchKernelGGL(k_attn1, dim3((NN * 64 + 255) / 256), dim3(256), 0, stream,
                     h1, as1, ad1, a1s, a1d);
  hipMemsetAsync(deg, 0, (size_t)NN * 4, stream);
  hipLaunchKernelGGL(k_hist, dim3((E2 + 255) / 256), dim3(256), 0, stream, ei, deg);
  hipLaunchKernelGGL(k_scan1, dim3(NB_SCAN), dim3(256), 0, stream, deg, bsum);
  hipLaunchKernelGGL(k_scan2, dim3(1), dim3(128), 0, stream, bsum, NB_SCAN);
  hipLaunchKernelGGL(k_scan3, dim3(NB_SCAN), dim3(256), 0, stream, deg, bsum, rowptr, cursor);
  hipLaunchKernelGGL(k_scatter, dim3((E2 + 255) / 256), dim3(256), 0, stream,
                     ei, ef, a1s, a1d, q, cursor, cpk);
  hipLaunchKernelGGL(k_agg1, dim3((NN * 64 + 255) / 256), dim3(256), 0, stream,
                     h1, rowptr, cpk, b1, W2, as2, ad2, h2, a2s, a2d);
  hipLaunchKernelGGL(k_agg2, dim3((NN * 64 + 255) / 256), dim3(256), 0, stream,
                     rowptr, cpk, h2, a2s, a2d, b2, out);
}

// Round 2
// 506.685 us; speedup vs baseline: 1.1855x; 1.1855x over previous
//
#include <hip/hip_runtime.h>
#include <hip/hip_bf16.h>

#define NN 100000
#define NE 1600000
#define E2 (NE + NN)          // edges + self loops
#define NEG_SLOPE 0.2f
#define GEPS 1e-16f

// ---------- tiny prep: q1[3][2] (layer1 edge-att vector), q2[3] (layer2) ----------
__global__ void k_prep(const float* __restrict__ We1, const float* __restrict__ ae1,
                       const float* __restrict__ We2, const float* __restrict__ ae2,
                       float* __restrict__ q) {
  int t = threadIdx.x;
  if (t < 6) {                       // q[d*2+hh] = sum_c We1[d, hh*64+c] * ae1[hh*64+c]
    int d = t >> 1, hh = t & 1;
    float s = 0.f;
    for (int c = 0; c < 64; ++c) s += We1[d * 128 + hh * 64 + c] * ae1[hh * 64 + c];
    q[t] = s;
  } else if (t < 9) {                // q[8+d] = sum_j We2[d,j]*ae2[j]
    int d = t - 6;
    q[8 + d] = We2[d * 2 + 0] * ae2[0] + We2[d * 2 + 1] * ae2[1];
  }
}

// ---------- layer1 GEMM: h1[N,128] = x[N,128] @ W1[128,128]  + fused attn scalars ----------
// W1 staged fully in LDS (64KB). Block = 256 thr, 32 rows x 128 cols per block,
// thread tile 4x4. Epilogue computes a1s/a1d per row via 16-lane shuffle reductions.
__global__ __launch_bounds__(256) void k_gemm(const float* __restrict__ x,
                                              const float* __restrict__ W,
                                              const float* __restrict__ as1g,
                                              const float* __restrict__ ad1g,
                                              float* __restrict__ h1,
                                              float* __restrict__ a1s,
                                              float* __restrict__ a1d) {
  __shared__ float ws[128 * 128];
  int t = threadIdx.x;
  for (int i = t * 4; i < 128 * 128; i += 1024)
    *(float4*)&ws[i] = *(const float4*)&W[i];
  __syncthreads();
  int row0 = blockIdx.x * 32;
  int tc = t & 31, tr = t >> 5;
  int c0 = tc * 4;
  int r0 = row0 + tr * 4;
  float acc[4][4];
#pragma unroll
  for (int r = 0; r < 4; ++r)
#pragma unroll
    for (int c = 0; c < 4; ++c) acc[r][c] = 0.f;

  for (int kk = 0; kk < 128; kk += 4) {
    float4 wv[4], xv[4];
#pragma unroll
    for (int j = 0; j < 4; ++j) wv[j] = *(const float4*)&ws[(kk + j) * 128 + c0];
#pragma unroll
    for (int r = 0; r < 4; ++r) xv[r] = *(const float4*)&x[(size_t)(r0 + r) * 128 + kk];
#pragma unroll
    for (int r = 0; r < 4; ++r) {
      acc[r][0] += xv[r].x * wv[0].x + xv[r].y * wv[1].x + xv[r].z * wv[2].x + xv[r].w * wv[3].x;
      acc[r][1] += xv[r].x * wv[0].y + xv[r].y * wv[1].y + xv[r].z * wv[2].y + xv[r].w * wv[3].y;
      acc[r][2] += xv[r].x * wv[0].z + xv[r].y * wv[1].z + xv[r].z * wv[2].z + xv[r].w * wv[3].z;
      acc[r][3] += xv[r].x * wv[0].w + xv[r].y * wv[1].w + xv[r].z * wv[2].w + xv[r].w * wv[3].w;
    }
  }
#pragma unroll
  for (int r = 0; r < 4; ++r) {
    float4 v = make_float4(acc[r][0], acc[r][1], acc[r][2], acc[r][3]);
    *(float4*)&h1[(size_t)(r0 + r) * 128 + c0] = v;
  }
  // fused attention scalars: a1s[row,h] = sum_c h[row,c]*as1[c] per head
  float4 av = *(const float4*)&as1g[c0];
  float4 dv = *(const float4*)&ad1g[c0];
  float ps[4], pd[4];
#pragma unroll
  for (int r = 0; r < 4; ++r) {
    ps[r] = acc[r][0] * av.x + acc[r][1] * av.y + acc[r][2] * av.z + acc[r][3] * av.w;
    pd[r] = acc[r][0] * dv.x + acc[r][1] * dv.y + acc[r][2] * dv.z + acc[r][3] * dv.w;
  }
#pragma unroll
  for (int o = 1; o <= 8; o <<= 1) {
#pragma unroll
    for (int r = 0; r < 4; ++r) {
      ps[r] += __shfl_xor(ps[r], o);
      pd[r] += __shfl_xor(pd[r], o);
    }
  }
  if (tc == 0 || tc == 16) {
    int hh = tc >> 4;
#pragma unroll
    for (int r = 0; r < 4; ++r) {
      a1s[(r0 + r) * 2 + hh] = ps[r];
      a1d[(r0 + r) * 2 + hh] = pd[r];
    }
  }
}

// ---------- CSR build ----------
__global__ void k_hist(const int* __restrict__ ei, int* __restrict__ deg) {
  int e = blockIdx.x * 256 + threadIdx.x;
  if (e >= E2) return;
  int dst = (e < NE) ? ei[NE + e] : (e - NE);
  atomicAdd(&deg[dst], 1);
}

__global__ void k_scan1(const int* __restrict__ deg, int* __restrict__ bsum) {
  __shared__ int lds[256];
  int t = threadIdx.x;
  int base = blockIdx.x * 1024 + t * 4;
  int s = 0;
  for (int j = 0; j < 4; ++j) { int i = base + j; s += (i < NN) ? deg[i] : 0; }
  lds[t] = s; __syncthreads();
  for (int o = 128; o > 0; o >>= 1) { if (t < o) lds[t] += lds[t + o]; __syncthreads(); }
  if (t == 0) bsum[blockIdx.x] = lds[0];
}

__global__ void k_scan2(int* __restrict__ bsum, int nb) {
  __shared__ int lds[128];
  int t = threadIdx.x;
  int v = (t < nb) ? bsum[t] : 0;
  lds[t] = v; __syncthreads();
  for (int o = 1; o < 128; o <<= 1) {
    int u = (t >= o) ? lds[t - o] : 0;
    __syncthreads();
    lds[t] += u;
    __syncthreads();
  }
  if (t < nb) bsum[t] = lds[t] - v;   // exclusive
}

__global__ void k_scan3(const int* __restrict__ deg, const int* __restrict__ bbase,
                        int* __restrict__ rowptr, int* __restrict__ cursor) {
  __shared__ int lds[256];
  int t = threadIdx.x;
  int base = blockIdx.x * 1024 + t * 4;
  int v[4]; int s = 0;
  for (int j = 0; j < 4; ++j) { int i = base + j; v[j] = (i < NN) ? deg[i] : 0; s += v[j]; }
  lds[t] = s; __syncthreads();
  for (int o = 1; o < 256; o <<= 1) {
    int u = (t >= o) ? lds[t - o] : 0;
    __syncthreads();
    lds[t] += u;
    __syncthreads();
  }
  int excl = lds[t] - s + bbase[blockIdx.x];
  for (int j = 0; j < 4; ++j) {
    int i = base + j;
    if (i <= NN) {
      rowptr[i] = excl;
      if (i < NN) cursor[i] = excl;
    }
    excl += v[j];
  }
}

// ---------- scatter edges into CSR, packing (alpha0, alpha1, src, ae2) per slot ----------
__global__ void k_scatter(const int* __restrict__ ei, const float* __restrict__ ef,
                          const float* __restrict__ a1s, const float* __restrict__ a1d,
                          const float* __restrict__ q, int* __restrict__ cursor,
                          float4* __restrict__ cpk) {
  int e = blockIdx.x * 256 + threadIdx.x;
  if (e >= E2) return;
  int src, dst; float e0, e1, ez;
  if (e < NE) {
    src = ei[e]; dst = ei[NE + e];
    float f0 = ef[(size_t)e * 3], f1 = ef[(size_t)e * 3 + 1], f2 = ef[(size_t)e * 3 + 2];
    e0 = f0 * q[0] + f1 * q[2] + f2 * q[4];
    e1 = f0 * q[1] + f1 * q[3] + f2 * q[5];
    ez = f0 * q[8] + f1 * q[9] + f2 * q[10];
  } else {
    src = dst = e - NE; e0 = e1 = ez = 0.f;   // self-loop, zero edge_attr
  }
  float al0 = a1s[src * 2] + a1d[dst * 2] + e0;
  float al1 = a1s[src * 2 + 1] + a1d[dst * 2 + 1] + e1;
  al0 = al0 > 0.f ? al0 : NEG_SLOPE * al0;
  al1 = al1 > 0.f ? al1 : NEG_SLOPE * al1;
  int pos = atomicAdd(&cursor[dst], 1);
  float4 pk;
  pk.x = al0; pk.y = al1; pk.z = __int_as_float(src); pk.w = ez;
  cpk[pos] = pk;
}

// ---------- layer1 aggregation + bias + ELU + layer2 projection epilogue ----------
// one wave per dst node; lane owns channel (lane) of head0 and (64+lane) of head1.
// No max-subtraction: alpha post-leakyrelu is bounded (|alpha| <~ 12), exp() is
// safely fp32-representable and softmax is shift-invariant; EPS stays negligible.
// Edge loop unrolled x4 for memory-level parallelism (12 loads in flight).
__global__ __launch_bounds__(256) void k_agg1(const float* __restrict__ h1,
                                              const int* __restrict__ rowptr,
                                              const float4* __restrict__ cpk,
                                              const float* __restrict__ b1,
                                              const float* __restrict__ W2,
                                              const float* __restrict__ as2,
                                              const float* __restrict__ ad2,
                                              float* __restrict__ h2,
                                              float* __restrict__ a2s, float* __restrict__ a2d) {
  int n = (int)((blockIdx.x * 256 + threadIdx.x) >> 6);
  int lane = threadIdx.x & 63;
  if (n >= NN) return;
  int s0 = rowptr[n], s1 = rowptr[n + 1];
  float acc0 = 0.f, acc1 = 0.f, d0 = 0.f, d1 = 0.f;
  int i = s0;
  for (; i + 4 <= s1; i += 4) {
    float4 pA = cpk[i], pB = cpk[i + 1], pC = cpk[i + 2], pD = cpk[i + 3];
    const float* rA = h1 + (size_t)__float_as_int(pA.z) * 128;
    const float* rB = h1 + (size_t)__float_as_int(pB.z) * 128;
    const float* rC = h1 + (size_t)__float_as_int(pC.z) * 128;
    const float* rD = h1 + (size_t)__float_as_int(pD.z) * 128;
    float hA0 = rA[lane], hA1 = rA[64 + lane];
    float hB0 = rB[lane], hB1 = rB[64 + lane];
    float hC0 = rC[lane], hC1 = rC[64 + lane];
    float hD0 = rD[lane], hD1 = rD[64 + lane];
    float eA0 = __expf(pA.x), eA1 = __expf(pA.y);
    float eB0 = __expf(pB.x), eB1 = __expf(pB.y);
    float eC0 = __expf(pC.x), eC1 = __expf(pC.y);
    float eD0 = __expf(pD.x), eD1 = __expf(pD.y);
    d0 += (eA0 + eB0) + (eC0 + eD0);
    d1 += (eA1 + eB1) + (eC1 + eD1);
    acc0 += eA0 * hA0 + eB0 * hB0 + eC0 * hC0 + eD0 * hD0;
    acc1 += eA1 * hA1 + eB1 * hB1 + eC1 * hC1 + eD1 * hD1;
  }
  for (; i < s1; ++i) {
    float4 pk = cpk[i];
    const float* r = h1 + (size_t)__float_as_int(pk.z) * 128;
    float e0 = __expf(pk.x), e1 = __expf(pk.y);
    d0 += e0; d1 += e1;
    acc0 += e0 * r[lane];
    acc1 += e1 * r[64 + lane];
  }
  float r0 = acc0 / (d0 + GEPS) + b1[lane];
  float r1 = acc1 / (d1 + GEPS) + b1[64 + lane];
  r0 = r0 > 0.f ? r0 : __expf(r0) - 1.f;   // ELU
  r1 = r1 > 0.f ? r1 : __expf(r1) - 1.f;
  // layer2 projection: h2[n,j] = sum_c elu_out[c] * W2[c,j]
  float p20 = r0 * W2[lane * 2 + 0] + r1 * W2[(64 + lane) * 2 + 0];
  float p21 = r0 * W2[lane * 2 + 1] + r1 * W2[(64 + lane) * 2 + 1];
  for (int o = 32; o > 0; o >>= 1) { p20 += __shfl_xor(p20, o); p21 += __shfl_xor(p21, o); }
  if (lane == 0) {
    h2[n * 2] = p20; h2[n * 2 + 1] = p21;
    a2s[n] = p20 * as2[0] + p21 * as2[1];
    a2d[n] = p20 * ad2[0] + p21 * ad2[1];
  }
}

// ---------- layer2 aggregation (lane-parallel; tiny channels; no max pass) ----------
__global__ __launch_bounds__(256) void k_agg2(const int* __restrict__ rowptr,
                                              const float4* __restrict__ cpk,
                                              const float* __restrict__ h2,
                                              const float* __restrict__ a2s,
                                              const float* __restrict__ a2d,
                                              const float* __restrict__ b2,
                                              float* __restrict__ out) {
  int n = (int)((blockIdx.x * 256 + threadIdx.x) >> 6);
  int lane = threadIdx.x & 63;
  if (n >= NN) return;
  int s0 = rowptr[n], s1 = rowptr[n + 1];
  float adn = a2d[n];
  const float2* h2v = (const float2*)h2;
  float den = 0.f, acc0 = 0.f, acc1 = 0.f;
  for (int i = s0 + lane; i < s1; i += 64) {
    float4 pk = cpk[i];
    int s = __float_as_int(pk.z);
    float v = a2s[s] + adn + pk.w;
    v = v > 0.f ? v : NEG_SLOPE * v;
    float p = __expf(v);
    float2 hv = h2v[s];
    den += p;
    acc0 += p * hv.x;
    acc1 += p * hv.y;
  }
  for (int o = 32; o > 0; o >>= 1) {
    den += __shfl_xor(den, o);
    acc0 += __shfl_xor(acc0, o);
    acc1 += __shfl_xor(acc1, o);
  }
  if (lane == 0) {
    out[n * 2] = acc0 / (den + GEPS) + b2[0];
    out[n * 2 + 1] = acc1 / (den + GEPS) + b2[1];
  }
}

extern "C" void kernel_launch(void* const* d_in, const int* in_sizes, int n_in,
                              void* d_out, int out_size, void* d_ws, size_t ws_size,
                              hipStream_t stream) {
  (void)in_sizes; (void)n_in; (void)out_size; (void)ws_size;
  const float* x   = (const float*)d_in[0];
  const int*   ei  = (const int*)d_in[1];
  const float* ef  = (const float*)d_in[2];
  const float* W1  = (const float*)d_in[3];
  const float* We1 = (const float*)d_in[4];
  const float* as1 = (const float*)d_in[5];
  const float* ad1 = (const float*)d_in[6];
  const float* ae1 = (const float*)d_in[7];
  const float* b1  = (const float*)d_in[8];
  const float* W2  = (const float*)d_in[9];
  const float* We2 = (const float*)d_in[10];
  const float* as2 = (const float*)d_in[11];
  const float* ad2 = (const float*)d_in[12];
  const float* ae2 = (const float*)d_in[13];
  const float* b2  = (const float*)d_in[14];
  float* out = (float*)d_out;

  char* w = (char*)d_ws;
  auto alloc = [&](size_t bytes) -> char* {
    char* p = w; w += (bytes + 255) & ~(size_t)255; return p;
  };
  float*  h1     = (float*)alloc((size_t)NN * 128 * 4);   // 51.2 MB
  float*  a1s    = (float*)alloc((size_t)NN * 2 * 4);
  float*  a1d    = (float*)alloc((size_t)NN * 2 * 4);
  float*  h2     = (float*)alloc((size_t)NN * 2 * 4);
  float*  a2s    = (float*)alloc((size_t)NN * 4);
  float*  a2d    = (float*)alloc((size_t)NN * 4);
  float*  q      = (float*)alloc(64);
  int*    deg    = (int*)alloc((size_t)NN * 4);
  int*    rowptr = (int*)alloc((size_t)(NN + 1) * 4);
  int*    cursor = (int*)alloc((size_t)NN * 4);
  int*    bsum   = (int*)alloc(128 * 4);
  float4* cpk    = (float4*)alloc((size_t)E2 * 16);       // 27.2 MB

  const int NB_SCAN = (NN + 1023) / 1024;                 // 98

  hipLaunchKernelGGL(k_prep, dim3(1), dim3(16), 0, stream, We1, ae1, We2, ae2, q);
  hipLaunchKernelGGL(k_gemm, dim3(NN / 32), dim3(256), 0, stream,
                     x, W1, as1, ad1, h1, a1s, a1d);
  hipMemsetAsync(deg, 0, (size_t)NN * 4, stream);
  hipLaunchKernelGGL(k_hist, dim3((E2 + 255) / 256), dim3(256), 0, stream, ei, deg);
  hipLaunchKernelGGL(k_scan1, dim3(NB_SCAN), dim3(256), 0, stream, deg, bsum);
  hipLaunchKernelGGL(k_scan2, dim3(1), dim3(128), 0, stream, bsum, NB_SCAN);
  hipLaunchKernelGGL(k_scan3, dim3(NB_SCAN), dim3(256), 0, stream, deg, bsum, rowptr, cursor);
  hipLaunchKernelGGL(k_scatter, dim3((E2 + 255) / 256), dim3(256), 0, stream,
                     ei, ef, a1s, a1d, q, cursor, cpk);
  hipLaunchKernelGGL(k_agg1, dim3((NN * 64 + 255) / 256), dim3(256), 0, stream,
                     h1, rowptr, cpk, b1, W2, as2, ad2, h2, a2s, a2d);
  hipLaunchKernelGGL(k_agg2, dim3((NN * 64 + 255) / 256), dim3(256), 0, stream,
                     rowptr, cpk, h2, a2s, a2d, b2, out);
}

// Round 3
// 468.435 us; speedup vs baseline: 1.2823x; 1.0817x over previous
//
#include <hip/hip_runtime.h>
#include <hip/hip_bf16.h>

#define NN 100000
#define NE 1600000
#define E2 (NE + NN)          // edges + self loops
#define NEG_SLOPE 0.2f
#define GEPS 1e-16f

// fp32 -> bf16 round-to-nearest-even
__device__ __forceinline__ unsigned short f2b(float f) {
  unsigned u = __float_as_uint(f);
  u += 0x7fffu + ((u >> 16) & 1u);
  return (unsigned short)(u >> 16);
}

// ---------- tiny prep: q1[3][2] (layer1 edge-att vector), q2[3] (layer2) ----------
__global__ void k_prep(const float* __restrict__ We1, const float* __restrict__ ae1,
                       const float* __restrict__ We2, const float* __restrict__ ae2,
                       float* __restrict__ q) {
  int t = threadIdx.x;
  if (t < 6) {                       // q[d*2+hh] = sum_c We1[d, hh*64+c] * ae1[hh*64+c]
    int d = t >> 1, hh = t & 1;
    float s = 0.f;
    for (int c = 0; c < 64; ++c) s += We1[d * 128 + hh * 64 + c] * ae1[hh * 64 + c];
    q[t] = s;
  } else if (t < 9) {                // q[8+d] = sum_j We2[d,j]*ae2[j]
    int d = t - 6;
    q[8 + d] = We2[d * 2 + 0] * ae2[0] + We2[d * 2 + 1] * ae2[1];
  }
}

// ---------- layer1 GEMM: h1[N,128] = x[N,128] @ W1[128,128]  + fused attn scalars ----------
// W1 staged fully in LDS (64KB). 32 rows x 128 cols per block, thread tile 4x4.
// h1 stored as bf16 (halves aggregation gather bytes); a1s/a1d computed from the
// fp32 accumulators so alpha is unaffected by the bf16 rounding.
__global__ __launch_bounds__(256) void k_gemm(const float* __restrict__ x,
                                              const float* __restrict__ W,
                                              const float* __restrict__ as1g,
                                              const float* __restrict__ ad1g,
                                              unsigned short* __restrict__ h1b,
                                              float* __restrict__ a1s,
                                              float* __restrict__ a1d) {
  __shared__ float ws[128 * 128];
  int t = threadIdx.x;
  for (int i = t * 4; i < 128 * 128; i += 1024)
    *(float4*)&ws[i] = *(const float4*)&W[i];
  __syncthreads();
  int row0 = blockIdx.x * 32;
  int tc = t & 31, tr = t >> 5;
  int c0 = tc * 4;
  int r0 = row0 + tr * 4;
  float acc[4][4];
#pragma unroll
  for (int r = 0; r < 4; ++r)
#pragma unroll
    for (int c = 0; c < 4; ++c) acc[r][c] = 0.f;

  for (int kk = 0; kk < 128; kk += 4) {
    float4 wv[4], xv[4];
#pragma unroll
    for (int j = 0; j < 4; ++j) wv[j] = *(const float4*)&ws[(kk + j) * 128 + c0];
#pragma unroll
    for (int r = 0; r < 4; ++r) xv[r] = *(const float4*)&x[(size_t)(r0 + r) * 128 + kk];
#pragma unroll
    for (int r = 0; r < 4; ++r) {
      acc[r][0] += xv[r].x * wv[0].x + xv[r].y * wv[1].x + xv[r].z * wv[2].x + xv[r].w * wv[3].x;
      acc[r][1] += xv[r].x * wv[0].y + xv[r].y * wv[1].y + xv[r].z * wv[2].y + xv[r].w * wv[3].y;
      acc[r][2] += xv[r].x * wv[0].z + xv[r].y * wv[1].z + xv[r].z * wv[2].z + xv[r].w * wv[3].z;
      acc[r][3] += xv[r].x * wv[0].w + xv[r].y * wv[1].w + xv[r].z * wv[2].w + xv[r].w * wv[3].w;
    }
  }
#pragma unroll
  for (int r = 0; r < 4; ++r) {
    uint2 st;
    st.x = (unsigned)f2b(acc[r][0]) | ((unsigned)f2b(acc[r][1]) << 16);
    st.y = (unsigned)f2b(acc[r][2]) | ((unsigned)f2b(acc[r][3]) << 16);
    *(uint2*)&h1b[(size_t)(r0 + r) * 128 + c0] = st;
  }
  // fused attention scalars from fp32 acc
  float4 av = *(const float4*)&as1g[c0];
  float4 dv = *(const float4*)&ad1g[c0];
  float ps[4], pd[4];
#pragma unroll
  for (int r = 0; r < 4; ++r) {
    ps[r] = acc[r][0] * av.x + acc[r][1] * av.y + acc[r][2] * av.z + acc[r][3] * av.w;
    pd[r] = acc[r][0] * dv.x + acc[r][1] * dv.y + acc[r][2] * dv.z + acc[r][3] * dv.w;
  }
#pragma unroll
  for (int o = 1; o <= 8; o <<= 1) {
#pragma unroll
    for (int r = 0; r < 4; ++r) {
      ps[r] += __shfl_xor(ps[r], o);
      pd[r] += __shfl_xor(pd[r], o);
    }
  }
  if (tc == 0 || tc == 16) {
    int hh = tc >> 4;
#pragma unroll
    for (int r = 0; r < 4; ++r) {
      a1s[(r0 + r) * 2 + hh] = ps[r];
      a1d[(r0 + r) * 2 + hh] = pd[r];
    }
  }
}

// ---------- CSR build ----------
__global__ void k_hist(const int* __restrict__ ei, int* __restrict__ deg) {
  int e = blockIdx.x * 256 + threadIdx.x;
  if (e >= E2) return;
  int dst = (e < NE) ? ei[NE + e] : (e - NE);
  atomicAdd(&deg[dst], 1);
}

__global__ void k_scan1(const int* __restrict__ deg, int* __restrict__ bsum) {
  __shared__ int lds[256];
  int t = threadIdx.x;
  int base = blockIdx.x * 1024 + t * 4;
  int s = 0;
  for (int j = 0; j < 4; ++j) { int i = base + j; s += (i < NN) ? deg[i] : 0; }
  lds[t] = s; __syncthreads();
  for (int o = 128; o > 0; o >>= 1) { if (t < o) lds[t] += lds[t + o]; __syncthreads(); }
  if (t == 0) bsum[blockIdx.x] = lds[0];
}

__global__ void k_scan2(int* __restrict__ bsum, int nb) {
  __shared__ int lds[128];
  int t = threadIdx.x;
  int v = (t < nb) ? bsum[t] : 0;
  lds[t] = v; __syncthreads();
  for (int o = 1; o < 128; o <<= 1) {
    int u = (t >= o) ? lds[t - o] : 0;
    __syncthreads();
    lds[t] += u;
    __syncthreads();
  }
  if (t < nb) bsum[t] = lds[t] - v;   // exclusive
}

__global__ void k_scan3(const int* __restrict__ deg, const int* __restrict__ bbase,
                        int* __restrict__ rowptr, int* __restrict__ cursor) {
  __shared__ int lds[256];
  int t = threadIdx.x;
  int base = blockIdx.x * 1024 + t * 4;
  int v[4]; int s = 0;
  for (int j = 0; j < 4; ++j) { int i = base + j; v[j] = (i < NN) ? deg[i] : 0; s += v[j]; }
  lds[t] = s; __syncthreads();
  for (int o = 1; o < 256; o <<= 1) {
    int u = (t >= o) ? lds[t - o] : 0;
    __syncthreads();
    lds[t] += u;
    __syncthreads();
  }
  int excl = lds[t] - s + bbase[blockIdx.x];
  for (int j = 0; j < 4; ++j) {
    int i = base + j;
    if (i <= NN) {
      rowptr[i] = excl;
      if (i < NN) cursor[i] = excl;
    }
    excl += v[j];
  }
}

// ---------- scatter edges into CSR, packing (exp0, exp1, src, ez) per slot ----------
// exp(leakyrelu(alpha)) precomputed here so the agg1 hot loop is pure FMA.
__global__ void k_scatter(const int* __restrict__ ei, const float* __restrict__ ef,
                          const float* __restrict__ a1s, const float* __restrict__ a1d,
                          const float* __restrict__ q, int* __restrict__ cursor,
                          float4* __restrict__ cpk) {
  int e = blockIdx.x * 256 + threadIdx.x;
  if (e >= E2) return;
  int src, dst; float e0, e1, ez;
  if (e < NE) {
    src = ei[e]; dst = ei[NE + e];
    float f0 = ef[(size_t)e * 3], f1 = ef[(size_t)e * 3 + 1], f2 = ef[(size_t)e * 3 + 2];
    e0 = f0 * q[0] + f1 * q[2] + f2 * q[4];
    e1 = f0 * q[1] + f1 * q[3] + f2 * q[5];
    ez = f0 * q[8] + f1 * q[9] + f2 * q[10];
  } else {
    src = dst = e - NE; e0 = e1 = ez = 0.f;   // self-loop, zero edge_attr
  }
  float al0 = a1s[src * 2] + a1d[dst * 2] + e0;
  float al1 = a1s[src * 2 + 1] + a1d[dst * 2 + 1] + e1;
  al0 = al0 > 0.f ? al0 : NEG_SLOPE * al0;
  al1 = al1 > 0.f ? al1 : NEG_SLOPE * al1;
  int pos = atomicAdd(&cursor[dst], 1);
  float4 pk;
  pk.x = __expf(al0); pk.y = __expf(al1); pk.z = __int_as_float(src); pk.w = ez;
  cpk[pos] = pk;
}

// ---------- layer1 aggregation + bias + ELU + layer2 projection epilogue ----------
// one wave per dst node; lane owns channel pair (2L, 2L+1): lanes 0-31 = head0,
// lanes 32-63 = head1 (per-lane softmax weight select). One dword gather per
// lane per edge (bf16x2). No max-subtraction (alpha bounded, shift-invariant).
__global__ __launch_bounds__(256) void k_agg1(const unsigned short* __restrict__ h1b,
                                              const int* __restrict__ rowptr,
                                              const float4* __restrict__ cpk,
                                              const float* __restrict__ b1,
                                              const float* __restrict__ W2,
                                              const float* __restrict__ as2,
                                              const float* __restrict__ ad2,
                                              float* __restrict__ h2,
                                              float* __restrict__ a2s, float* __restrict__ a2d) {
  int n = (int)((blockIdx.x * 256 + threadIdx.x) >> 6);
  int lane = threadIdx.x & 63;
  if (n >= NN) return;
  int s0 = rowptr[n], s1 = rowptr[n + 1];
  bool hi = lane >= 32;
  float acc0 = 0.f, acc1 = 0.f, den = 0.f;
  int i = s0;
  for (; i + 4 <= s1; i += 4) {
    float4 pA = cpk[i], pB = cpk[i + 1], pC = cpk[i + 2], pD = cpk[i + 3];
    unsigned vA = *(const unsigned*)&h1b[(size_t)__float_as_int(pA.z) * 128 + lane * 2];
    unsigned vB = *(const unsigned*)&h1b[(size_t)__float_as_int(pB.z) * 128 + lane * 2];
    unsigned vC = *(const unsigned*)&h1b[(size_t)__float_as_int(pC.z) * 128 + lane * 2];
    unsigned vD = *(const unsigned*)&h1b[(size_t)__float_as_int(pD.z) * 128 + lane * 2];
    float eA = hi ? pA.y : pA.x;
    float eB = hi ? pB.y : pB.x;
    float eC = hi ? pC.y : pC.x;
    float eD = hi ? pD.y : pD.x;
    den += (eA + eB) + (eC + eD);
    acc0 += eA * __uint_as_float(vA << 16) + eB * __uint_as_float(vB << 16)
          + eC * __uint_as_float(vC << 16) + eD * __uint_as_float(vD << 16);
    acc1 += eA * __uint_as_float(vA & 0xffff0000u) + eB * __uint_as_float(vB & 0xffff0000u)
          + eC * __uint_as_float(vC & 0xffff0000u) + eD * __uint_as_float(vD & 0xffff0000u);
  }
  for (; i < s1; ++i) {
    float4 pk = cpk[i];
    unsigned v = *(const unsigned*)&h1b[(size_t)__float_as_int(pk.z) * 128 + lane * 2];
    float e = hi ? pk.y : pk.x;
    den += e;
    acc0 += e * __uint_as_float(v << 16);
    acc1 += e * __uint_as_float(v & 0xffff0000u);
  }
  float2 bv = *(const float2*)&b1[lane * 2];
  float r0 = acc0 / (den + GEPS) + bv.x;
  float r1 = acc1 / (den + GEPS) + bv.y;
  r0 = r0 > 0.f ? r0 : __expf(r0) - 1.f;   // ELU
  r1 = r1 > 0.f ? r1 : __expf(r1) - 1.f;
  // layer2 projection: channels (2L, 2L+1) -> W2 rows 2L, 2L+1 (float4 at W2+4L)
  float4 wv = *(const float4*)&W2[lane * 4];
  float p20 = r0 * wv.x + r1 * wv.z;
  float p21 = r0 * wv.y + r1 * wv.w;
  for (int o = 32; o > 0; o >>= 1) { p20 += __shfl_xor(p20, o); p21 += __shfl_xor(p21, o); }
  if (lane == 0) {
    h2[n * 2] = p20; h2[n * 2 + 1] = p21;
    a2s[n] = p20 * as2[0] + p21 * as2[1];
    a2d[n] = p20 * ad2[0] + p21 * ad2[1];
  }
}

// ---------- layer2 aggregation (lane-parallel; tiny channels; no max pass) ----------
__global__ __launch_bounds__(256) void k_agg2(const int* __restrict__ rowptr,
                                              const float4* __restrict__ cpk,
                                              const float* __restrict__ h2,
                                              const float* __restrict__ a2s,
                                              const float* __restrict__ a2d,
                                              const float* __restrict__ b2,
                                              float* __restrict__ out) {
  int n = (int)((blockIdx.x * 256 + threadIdx.x) >> 6);
  int lane = threadIdx.x & 63;
  if (n >= NN) return;
  int s0 = rowptr[n], s1 = rowptr[n + 1];
  float adn = a2d[n];
  const float2* h2v = (const float2*)h2;
  float den = 0.f, acc0 = 0.f, acc1 = 0.f;
  for (int i = s0 + lane; i < s1; i += 64) {
    float4 pk = cpk[i];
    int s = __float_as_int(pk.z);
    float v = a2s[s] + adn + pk.w;
    v = v > 0.f ? v : NEG_SLOPE * v;
    float p = __expf(v);
    float2 hv = h2v[s];
    den += p;
    acc0 += p * hv.x;
    acc1 += p * hv.y;
  }
  for (int o = 32; o > 0; o >>= 1) {
    den += __shfl_xor(den, o);
    acc0 += __shfl_xor(acc0, o);
    acc1 += __shfl_xor(acc1, o);
  }
  if (lane == 0) {
    out[n * 2] = acc0 / (den + GEPS) + b2[0];
    out[n * 2 + 1] = acc1 / (den + GEPS) + b2[1];
  }
}

extern "C" void kernel_launch(void* const* d_in, const int* in_sizes, int n_in,
                              void* d_out, int out_size, void* d_ws, size_t ws_size,
                              hipStream_t stream) {
  (void)in_sizes; (void)n_in; (void)out_size; (void)ws_size;
  const float* x   = (const float*)d_in[0];
  const int*   ei  = (const int*)d_in[1];
  const float* ef  = (const float*)d_in[2];
  const float* W1  = (const float*)d_in[3];
  const float* We1 = (const float*)d_in[4];
  const float* as1 = (const float*)d_in[5];
  const float* ad1 = (const float*)d_in[6];
  const float* ae1 = (const float*)d_in[7];
  const float* b1  = (const float*)d_in[8];
  const float* W2  = (const float*)d_in[9];
  const float* We2 = (const float*)d_in[10];
  const float* as2 = (const float*)d_in[11];
  const float* ad2 = (const float*)d_in[12];
  const float* ae2 = (const float*)d_in[13];
  const float* b2  = (const float*)d_in[14];
  float* out = (float*)d_out;

  char* w = (char*)d_ws;
  auto alloc = [&](size_t bytes) -> char* {
    char* p = w; w += (bytes + 255) & ~(size_t)255; return p;
  };
  unsigned short* h1b = (unsigned short*)alloc((size_t)NN * 128 * 2);  // 25.6 MB
  float*  a1s    = (float*)alloc((size_t)NN * 2 * 4);
  float*  a1d    = (float*)alloc((size_t)NN * 2 * 4);
  float*  h2     = (float*)alloc((size_t)NN * 2 * 4);
  float*  a2s    = (float*)alloc((size_t)NN * 4);
  float*  a2d    = (float*)alloc((size_t)NN * 4);
  float*  q      = (float*)alloc(64);
  int*    deg    = (int*)alloc((size_t)NN * 4);
  int*    rowptr = (int*)alloc((size_t)(NN + 1) * 4);
  int*    cursor = (int*)alloc((size_t)NN * 4);
  int*    bsum   = (int*)alloc(128 * 4);
  float4* cpk    = (float4*)alloc((size_t)E2 * 16);       // 27.2 MB

  const int NB_SCAN = (NN + 1023) / 1024;                 // 98

  hipLaunchKernelGGL(k_prep, dim3(1), dim3(16), 0, stream, We1, ae1, We2, ae2, q);
  hipLaunchKernelGGL(k_gemm, dim3(NN / 32), dim3(256), 0, stream,
                     x, W1, as1, ad1, h1b, a1s, a1d);
  hipMemsetAsync(deg, 0, (size_t)NN * 4, stream);
  hipLaunchKernelGGL(k_hist, dim3((E2 + 255) / 256), dim3(256), 0, stream, ei, deg);
  hipLaunchKernelGGL(k_scan1, dim3(NB_SCAN), dim3(256), 0, stream, deg, bsum);
  hipLaunchKernelGGL(k_scan2, dim3(1), dim3(128), 0, stream, bsum, NB_SCAN);
  hipLaunchKernelGGL(k_scan3, dim3(NB_SCAN), dim3(256), 0, stream, deg, bsum, rowptr, cursor);
  hipLaunchKernelGGL(k_scatter, dim3((E2 + 255) / 256), dim3(256), 0, stream,
                     ei, ef, a1s, a1d, q, cursor, cpk);
  hipLaunchKernelGGL(k_agg1, dim3((NN * 64 + 255) / 256), dim3(256), 0, stream,
                     h1b, rowptr, cpk, b1, W2, as2, ad2, h2, a2s, a2d);
  hipLaunchKernelGGL(k_agg2, dim3((NN * 64 + 255) / 256), dim3(256), 0, stream,
                     rowptr, cpk, h2, a2s, a2d, b2, out);
}

// Round 4
// 461.208 us; speedup vs baseline: 1.3024x; 1.0157x over previous
//
#include <hip/hip_runtime.h>
#include <hip/hip_bf16.h>

#define NN 100000
#define NE 1600000
#define E2 (NE + NN)          // edges + self loops
#define NEG_SLOPE 0.2f
#define GEPS 1e-16f

// fp32 -> bf16 round-to-nearest-even
__device__ __forceinline__ unsigned short f2b(float f) {
  unsigned u = __float_as_uint(f);
  u += 0x7fffu + ((u >> 16) & 1u);
  return (unsigned short)(u >> 16);
}

// ---------- tiny prep: q1[3][2] (layer1 edge-att vector), q2[3] (layer2) ----------
__global__ void k_prep(const float* __restrict__ We1, const float* __restrict__ ae1,
                       const float* __restrict__ We2, const float* __restrict__ ae2,
                       float* __restrict__ q) {
  int t = threadIdx.x;
  if (t < 6) {                       // q[d*2+hh] = sum_c We1[d, hh*64+c] * ae1[hh*64+c]
    int d = t >> 1, hh = t & 1;
    float s = 0.f;
    for (int c = 0; c < 64; ++c) s += We1[d * 128 + hh * 64 + c] * ae1[hh * 64 + c];
    q[t] = s;
  } else if (t < 9) {                // q[8+d] = sum_j We2[d,j]*ae2[j]
    int d = t - 6;
    q[8 + d] = We2[d * 2 + 0] * ae2[0] + We2[d * 2 + 1] * ae2[1];
  }
}

// ---------- layer1 GEMM: h1[N,128] = x[N,128] @ W1[128,128]  + fused attn scalars ----------
// W1 fully in LDS (64KB). 512 threads, 128 rows/block, thread tile 8 rows x 4 cols.
// f/l = 128 FMA : 4 ds_read_b128 = 32 -> FMA-bound, not LDS-port-bound.
// 2 blocks/CU (LDS-capped) = 16 waves/CU. Row overflow clamped (benign dup stores).
__global__ __launch_bounds__(512) void k_gemm(const float* __restrict__ x,
                                              const float* __restrict__ W,
                                              const float* __restrict__ as1g,
                                              const float* __restrict__ ad1g,
                                              unsigned short* __restrict__ h1b,
                                              float* __restrict__ a1s,
                                              float* __restrict__ a1d) {
  __shared__ float ws[128 * 128];
  int t = threadIdx.x;
  for (int i = t * 4; i < 128 * 128; i += 2048)
    *(float4*)&ws[i] = *(const float4*)&W[i];
  __syncthreads();
  int row0 = blockIdx.x * 128;
  int tc = t & 31, tr = t >> 5;      // tr 0..15
  int c0 = tc * 4;
  int r0 = row0 + tr * 8;
  int row[8];
#pragma unroll
  for (int r = 0; r < 8; ++r) { int rr = r0 + r; row[r] = rr < NN ? rr : NN - 1; }

  float acc[8][4];
#pragma unroll
  for (int r = 0; r < 8; ++r)
#pragma unroll
    for (int c = 0; c < 4; ++c) acc[r][c] = 0.f;

  for (int kk = 0; kk < 128; kk += 4) {
    float4 wv[4], xv[8];
#pragma unroll
    for (int j = 0; j < 4; ++j) wv[j] = *(const float4*)&ws[(kk + j) * 128 + c0];
#pragma unroll
    for (int r = 0; r < 8; ++r) xv[r] = *(const float4*)&x[(size_t)row[r] * 128 + kk];
#pragma unroll
    for (int r = 0; r < 8; ++r) {
      acc[r][0] += xv[r].x * wv[0].x + xv[r].y * wv[1].x + xv[r].z * wv[2].x + xv[r].w * wv[3].x;
      acc[r][1] += xv[r].x * wv[0].y + xv[r].y * wv[1].y + xv[r].z * wv[2].y + xv[r].w * wv[3].y;
      acc[r][2] += xv[r].x * wv[0].z + xv[r].y * wv[1].z + xv[r].z * wv[2].z + xv[r].w * wv[3].z;
      acc[r][3] += xv[r].x * wv[0].w + xv[r].y * wv[1].w + xv[r].z * wv[2].w + xv[r].w * wv[3].w;
    }
  }
#pragma unroll
  for (int r = 0; r < 8; ++r) {
    uint2 st;
    st.x = (unsigned)f2b(acc[r][0]) | ((unsigned)f2b(acc[r][1]) << 16);
    st.y = (unsigned)f2b(acc[r][2]) | ((unsigned)f2b(acc[r][3]) << 16);
    *(uint2*)&h1b[(size_t)row[r] * 128 + c0] = st;
  }
  // fused attention scalars from fp32 acc
  float4 av = *(const float4*)&as1g[c0];
  float4 dv = *(const float4*)&ad1g[c0];
  float ps[8], pd[8];
#pragma unroll
  for (int r = 0; r < 8; ++r) {
    ps[r] = acc[r][0] * av.x + acc[r][1] * av.y + acc[r][2] * av.z + acc[r][3] * av.w;
    pd[r] = acc[r][0] * dv.x + acc[r][1] * dv.y + acc[r][2] * dv.z + acc[r][3] * dv.w;
  }
#pragma unroll
  for (int o = 1; o <= 8; o <<= 1) {
#pragma unroll
    for (int r = 0; r < 8; ++r) {
      ps[r] += __shfl_xor(ps[r], o);
      pd[r] += __shfl_xor(pd[r], o);
    }
  }
  if (tc == 0 || tc == 16) {
    int hh = tc >> 4;
#pragma unroll
    for (int r = 0; r < 8; ++r) {
      a1s[row[r] * 2 + hh] = ps[r];
      a1d[row[r] * 2 + hh] = pd[r];
    }
  }
}

// ---------- CSR build ----------
__global__ void k_hist(const int* __restrict__ ei, int* __restrict__ deg) {
  int e = blockIdx.x * 256 + threadIdx.x;
  if (e >= E2) return;
  int dst = (e < NE) ? ei[NE + e] : (e - NE);
  atomicAdd(&deg[dst], 1);
}

__global__ void k_scan1(const int* __restrict__ deg, int* __restrict__ bsum) {
  __shared__ int lds[256];
  int t = threadIdx.x;
  int base = blockIdx.x * 1024 + t * 4;
  int s = 0;
  for (int j = 0; j < 4; ++j) { int i = base + j; s += (i < NN) ? deg[i] : 0; }
  lds[t] = s; __syncthreads();
  for (int o = 128; o > 0; o >>= 1) { if (t < o) lds[t] += lds[t + o]; __syncthreads(); }
  if (t == 0) bsum[blockIdx.x] = lds[0];
}

__global__ void k_scan2(int* __restrict__ bsum, int nb) {
  __shared__ int lds[128];
  int t = threadIdx.x;
  int v = (t < nb) ? bsum[t] : 0;
  lds[t] = v; __syncthreads();
  for (int o = 1; o < 128; o <<= 1) {
    int u = (t >= o) ? lds[t - o] : 0;
    __syncthreads();
    lds[t] += u;
    __syncthreads();
  }
  if (t < nb) bsum[t] = lds[t] - v;   // exclusive
}

__global__ void k_scan3(const int* __restrict__ deg, const int* __restrict__ bbase,
                        int* __restrict__ rowptr, int* __restrict__ cursor) {
  __shared__ int lds[256];
  int t = threadIdx.x;
  int base = blockIdx.x * 1024 + t * 4;
  int v[4]; int s = 0;
  for (int j = 0; j < 4; ++j) { int i = base + j; v[j] = (i < NN) ? deg[i] : 0; s += v[j]; }
  lds[t] = s; __syncthreads();
  for (int o = 1; o < 256; o <<= 1) {
    int u = (t >= o) ? lds[t - o] : 0;
    __syncthreads();
    lds[t] += u;
    __syncthreads();
  }
  int excl = lds[t] - s + bbase[blockIdx.x];
  for (int j = 0; j < 4; ++j) {
    int i = base + j;
    if (i <= NN) {
      rowptr[i] = excl;
      if (i < NN) cursor[i] = excl;
    }
    excl += v[j];
  }
}

// ---------- scatter edges into CSR, packing (exp0, exp1, src, ez) per slot ----------
__global__ void k_scatter(const int* __restrict__ ei, const float* __restrict__ ef,
                          const float* __restrict__ a1s, const float* __restrict__ a1d,
                          const float* __restrict__ q, int* __restrict__ cursor,
                          float4* __restrict__ cpk) {
  int e = blockIdx.x * 256 + threadIdx.x;
  if (e >= E2) return;
  int src, dst; float e0, e1, ez;
  if (e < NE) {
    src = ei[e]; dst = ei[NE + e];
    float f0 = ef[(size_t)e * 3], f1 = ef[(size_t)e * 3 + 1], f2 = ef[(size_t)e * 3 + 2];
    e0 = f0 * q[0] + f1 * q[2] + f2 * q[4];
    e1 = f0 * q[1] + f1 * q[3] + f2 * q[5];
    ez = f0 * q[8] + f1 * q[9] + f2 * q[10];
  } else {
    src = dst = e - NE; e0 = e1 = ez = 0.f;   // self-loop, zero edge_attr
  }
  float al0 = a1s[src * 2] + a1d[dst * 2] + e0;
  float al1 = a1s[src * 2 + 1] + a1d[dst * 2 + 1] + e1;
  al0 = al0 > 0.f ? al0 : NEG_SLOPE * al0;
  al1 = al1 > 0.f ? al1 : NEG_SLOPE * al1;
  int pos = atomicAdd(&cursor[dst], 1);
  float4 pk;
  pk.x = __expf(al0); pk.y = __expf(al1); pk.z = __int_as_float(src); pk.w = ez;
  cpk[pos] = pk;
}

// ---------- layer1 aggregation + bias + ELU + layer2 projection epilogue ----------
// one wave per dst node; lane owns channel pair (2L, 2L+1): lanes 0-31 = head0,
// lanes 32-63 = head1 (per-lane softmax weight select). One dword gather per
// lane per edge (bf16x2). No max-subtraction (alpha bounded, shift-invariant).
__global__ __launch_bounds__(256) void k_agg1(const unsigned short* __restrict__ h1b,
                                              const int* __restrict__ rowptr,
                                              const float4* __restrict__ cpk,
                                              const float* __restrict__ b1,
                                              const float* __restrict__ W2,
                                              const float* __restrict__ as2,
                                              const float* __restrict__ ad2,
                                              float* __restrict__ h2,
                                              float* __restrict__ a2s, float* __restrict__ a2d) {
  int n = (int)((blockIdx.x * 256 + threadIdx.x) >> 6);
  int lane = threadIdx.x & 63;
  if (n >= NN) return;
  int s0 = rowptr[n], s1 = rowptr[n + 1];
  bool hi = lane >= 32;
  float acc0 = 0.f, acc1 = 0.f, den = 0.f;
  int i = s0;
  for (; i + 4 <= s1; i += 4) {
    float4 pA = cpk[i], pB = cpk[i + 1], pC = cpk[i + 2], pD = cpk[i + 3];
    unsigned vA = *(const unsigned*)&h1b[(size_t)__float_as_int(pA.z) * 128 + lane * 2];
    unsigned vB = *(const unsigned*)&h1b[(size_t)__float_as_int(pB.z) * 128 + lane * 2];
    unsigned vC = *(const unsigned*)&h1b[(size_t)__float_as_int(pC.z) * 128 + lane * 2];
    unsigned vD = *(const unsigned*)&h1b[(size_t)__float_as_int(pD.z) * 128 + lane * 2];
    float eA = hi ? pA.y : pA.x;
    float eB = hi ? pB.y : pB.x;
    float eC = hi ? pC.y : pC.x;
    float eD = hi ? pD.y : pD.x;
    den += (eA + eB) + (eC + eD);
    acc0 += eA * __uint_as_float(vA << 16) + eB * __uint_as_float(vB << 16)
          + eC * __uint_as_float(vC << 16) + eD * __uint_as_float(vD << 16);
    acc1 += eA * __uint_as_float(vA & 0xffff0000u) + eB * __uint_as_float(vB & 0xffff0000u)
          + eC * __uint_as_float(vC & 0xffff0000u) + eD * __uint_as_float(vD & 0xffff0000u);
  }
  for (; i < s1; ++i) {
    float4 pk = cpk[i];
    unsigned v = *(const unsigned*)&h1b[(size_t)__float_as_int(pk.z) * 128 + lane * 2];
    float e = hi ? pk.y : pk.x;
    den += e;
    acc0 += e * __uint_as_float(v << 16);
    acc1 += e * __uint_as_float(v & 0xffff0000u);
  }
  float2 bv = *(const float2*)&b1[lane * 2];
  float r0 = acc0 / (den + GEPS) + bv.x;
  float r1 = acc1 / (den + GEPS) + bv.y;
  r0 = r0 > 0.f ? r0 : __expf(r0) - 1.f;   // ELU
  r1 = r1 > 0.f ? r1 : __expf(r1) - 1.f;
  // layer2 projection: channels (2L, 2L+1) -> W2 rows 2L, 2L+1 (float4 at W2+4L)
  float4 wv = *(const float4*)&W2[lane * 4];
  float p20 = r0 * wv.x + r1 * wv.z;
  float p21 = r0 * wv.y + r1 * wv.w;
  for (int o = 32; o > 0; o >>= 1) { p20 += __shfl_xor(p20, o); p21 += __shfl_xor(p21, o); }
  if (lane == 0) {
    h2[n * 2] = p20; h2[n * 2 + 1] = p21;
    a2s[n] = p20 * as2[0] + p21 * as2[1];
    a2d[n] = p20 * ad2[0] + p21 * ad2[1];
  }
}

// ---------- layer2 aggregation (lane-parallel; tiny channels; no max pass) ----------
__global__ __launch_bounds__(256) void k_agg2(const int* __restrict__ rowptr,
                                              const float4* __restrict__ cpk,
                                              const float* __restrict__ h2,
                                              const float* __restrict__ a2s,
                                              const float* __restrict__ a2d,
                                              const float* __restrict__ b2,
                                              float* __restrict__ out) {
  int n = (int)((blockIdx.x * 256 + threadIdx.x) >> 6);
  int lane = threadIdx.x & 63;
  if (n >= NN) return;
  int s0 = rowptr[n], s1 = rowptr[n + 1];
  float adn = a2d[n];
  const float2* h2v = (const float2*)h2;
  float den = 0.f, acc0 = 0.f, acc1 = 0.f;
  for (int i = s0 + lane; i < s1; i += 64) {
    float4 pk = cpk[i];
    int s = __float_as_int(pk.z);
    float v = a2s[s] + adn + pk.w;
    v = v > 0.f ? v : NEG_SLOPE * v;
    float p = __expf(v);
    float2 hv = h2v[s];
    den += p;
    acc0 += p * hv.x;
    acc1 += p * hv.y;
  }
  for (int o = 32; o > 0; o >>= 1) {
    den += __shfl_xor(den, o);
    acc0 += __shfl_xor(acc0, o);
    acc1 += __shfl_xor(acc1, o);
  }
  if (lane == 0) {
    out[n * 2] = acc0 / (den + GEPS) + b2[0];
    out[n * 2 + 1] = acc1 / (den + GEPS) + b2[1];
  }
}

extern "C" void kernel_launch(void* const* d_in, const int* in_sizes, int n_in,
                              void* d_out, int out_size, void* d_ws, size_t ws_size,
                              hipStream_t stream) {
  (void)in_sizes; (void)n_in; (void)out_size; (void)ws_size;
  const float* x   = (const float*)d_in[0];
  const int*   ei  = (const int*)d_in[1];
  const float* ef  = (const float*)d_in[2];
  const float* W1  = (const float*)d_in[3];
  const float* We1 = (const float*)d_in[4];
  const float* as1 = (const float*)d_in[5];
  const float* ad1 = (const float*)d_in[6];
  const float* ae1 = (const float*)d_in[7];
  const float* b1  = (const float*)d_in[8];
  const float* W2  = (const float*)d_in[9];
  const float* We2 = (const float*)d_in[10];
  const float* as2 = (const float*)d_in[11];
  const float* ad2 = (const float*)d_in[12];
  const float* ae2 = (const float*)d_in[13];
  const float* b2  = (const float*)d_in[14];
  float* out = (float*)d_out;

  char* w = (char*)d_ws;
  auto alloc = [&](size_t bytes) -> char* {
    char* p = w; w += (bytes + 255) & ~(size_t)255; return p;
  };
  unsigned short* h1b = (unsigned short*)alloc((size_t)NN * 128 * 2);  // 25.6 MB
  float*  a1s    = (float*)alloc((size_t)NN * 2 * 4);
  float*  a1d    = (float*)alloc((size_t)NN * 2 * 4);
  float*  h2     = (float*)alloc((size_t)NN * 2 * 4);
  float*  a2s    = (float*)alloc((size_t)NN * 4);
  float*  a2d    = (float*)alloc((size_t)NN * 4);
  float*  q      = (float*)alloc(64);
  int*    deg    = (int*)alloc((size_t)NN * 4);
  int*    rowptr = (int*)alloc((size_t)(NN + 1) * 4);
  int*    cursor = (int*)alloc((size_t)NN * 4);
  int*    bsum   = (int*)alloc(128 * 4);
  float4* cpk    = (float4*)alloc((size_t)E2 * 16);       // 27.2 MB

  const int NB_SCAN = (NN + 1023) / 1024;                 // 98

  hipLaunchKernelGGL(k_prep, dim3(1), dim3(16), 0, stream, We1, ae1, We2, ae2, q);
  hipLaunchKernelGGL(k_gemm, dim3((NN + 127) / 128), dim3(512), 0, stream,
                     x, W1, as1, ad1, h1b, a1s, a1d);
  hipMemsetAsync(deg, 0, (size_t)NN * 4, stream);
  hipLaunchKernelGGL(k_hist, dim3((E2 + 255) / 256), dim3(256), 0, stream, ei, deg);
  hipLaunchKernelGGL(k_scan1, dim3(NB_SCAN), dim3(256), 0, stream, deg, bsum);
  hipLaunchKernelGGL(k_scan2, dim3(1), dim3(128), 0, stream, bsum, NB_SCAN);
  hipLaunchKernelGGL(k_scan3, dim3(NB_SCAN), dim3(256), 0, stream, deg, bsum, rowptr, cursor);
  hipLaunchKernelGGL(k_scatter, dim3((E2 + 255) / 256), dim3(256), 0, stream,
                     ei, ef, a1s, a1d, q, cursor, cpk);
  hipLaunchKernelGGL(k_agg1, dim3((NN * 64 + 255) / 256), dim3(256), 0, stream,
                     h1b, rowptr, cpk, b1, W2, as2, ad2, h2, a2s, a2d);
  hipLaunchKernelGGL(k_agg2, dim3((NN * 64 + 255) / 256), dim3(256), 0, stream,
                     rowptr, cpk, h2, a2s, a2d, b2, out);
}

// Round 5
// 452.019 us; speedup vs baseline: 1.3288x; 1.0203x over previous
//
#include <hip/hip_runtime.h>
#include <hip/hip_bf16.h>

#define NN 100000
#define NE 1600000
#define E2 (NE + NN)          // edges + self loops
#define NEG_SLOPE 0.2f
#define GEPS 1e-16f

// fp32 -> bf16 round-to-nearest-even
__device__ __forceinline__ unsigned short f2b(float f) {
  unsigned u = __float_as_uint(f);
  u += 0x7fffu + ((u >> 16) & 1u);
  return (unsigned short)(u >> 16);
}
__device__ __forceinline__ float blo(unsigned u) { return __uint_as_float(u << 16); }
__device__ __forceinline__ float bhi(unsigned u) { return __uint_as_float(u & 0xffff0000u); }

// ---------- tiny prep: q1[3][2] (layer1 edge-att vector), q2[3] (layer2) ----------
__global__ void k_prep(const float* __restrict__ We1, const float* __restrict__ ae1,
                       const float* __restrict__ We2, const float* __restrict__ ae2,
                       float* __restrict__ q) {
  int t = threadIdx.x;
  if (t < 6) {
    int d = t >> 1, hh = t & 1;
    float s = 0.f;
    for (int c = 0; c < 64; ++c) s += We1[d * 128 + hh * 64 + c] * ae1[hh * 64 + c];
    q[t] = s;
  } else if (t < 9) {
    int d = t - 6;
    q[8 + d] = We2[d * 2 + 0] * ae2[0] + We2[d * 2 + 1] * ae2[1];
  }
}

// ---------- layer1 GEMM + fused attn scalars ----------
// W1 fully in LDS (64KB). 512 thr, 128 rows/block, 8x4 tile.
// __launch_bounds__(512,4): cap VGPR<=128 so 2 blocks/CU = 16 waves (round-4
// failure: no bound -> >128 VGPR -> 1 block/CU = 25% occ). xv staged 4 rows
// at a time to shrink live range.
__global__ __launch_bounds__(512, 4) void k_gemm(const float* __restrict__ x,
                                                 const float* __restrict__ W,
                                                 const float* __restrict__ as1g,
                                                 const float* __restrict__ ad1g,
                                                 unsigned short* __restrict__ h1b,
                                                 float* __restrict__ a1s,
                                                 float* __restrict__ a1d) {
  __shared__ float ws[128 * 128];
  int t = threadIdx.x;
  for (int i = t * 4; i < 128 * 128; i += 2048)
    *(float4*)&ws[i] = *(const float4*)&W[i];
  __syncthreads();
  int tc = t & 31, tr = t >> 5;      // tc: 32 col-threads x4 = 128 cols; tr: 16 x 8 rows
  int c0 = tc * 4;
  int r0 = blockIdx.x * 128 + tr * 8;
  int row[8];
#pragma unroll
  for (int r = 0; r < 8; ++r) { int rr = r0 + r; row[r] = rr < NN ? rr : NN - 1; }

  float acc[8][4];
#pragma unroll
  for (int r = 0; r < 8; ++r)
#pragma unroll
    for (int c = 0; c < 4; ++c) acc[r][c] = 0.f;

  for (int kk = 0; kk < 128; kk += 4) {
    float4 wv0 = *(const float4*)&ws[(kk + 0) * 128 + c0];
    float4 wv1 = *(const float4*)&ws[(kk + 1) * 128 + c0];
    float4 wv2 = *(const float4*)&ws[(kk + 2) * 128 + c0];
    float4 wv3 = *(const float4*)&ws[(kk + 3) * 128 + c0];
#pragma unroll
    for (int half = 0; half < 2; ++half) {
      float4 xv[4];
#pragma unroll
      for (int r = 0; r < 4; ++r)
        xv[r] = *(const float4*)&x[(size_t)row[half * 4 + r] * 128 + kk];
#pragma unroll
      for (int r = 0; r < 4; ++r) {
        int rr = half * 4 + r;
        acc[rr][0] += xv[r].x * wv0.x + xv[r].y * wv1.x + xv[r].z * wv2.x + xv[r].w * wv3.x;
        acc[rr][1] += xv[r].x * wv0.y + xv[r].y * wv1.y + xv[r].z * wv2.y + xv[r].w * wv3.y;
        acc[rr][2] += xv[r].x * wv0.z + xv[r].y * wv1.z + xv[r].z * wv2.z + xv[r].w * wv3.z;
        acc[rr][3] += xv[r].x * wv0.w + xv[r].y * wv1.w + xv[r].z * wv2.w + xv[r].w * wv3.w;
      }
    }
  }
#pragma unroll
  for (int r = 0; r < 8; ++r) {
    uint2 st;
    st.x = (unsigned)f2b(acc[r][0]) | ((unsigned)f2b(acc[r][1]) << 16);
    st.y = (unsigned)f2b(acc[r][2]) | ((unsigned)f2b(acc[r][3]) << 16);
    *(uint2*)&h1b[(size_t)row[r] * 128 + c0] = st;
  }
  // fused attention scalars from fp32 acc (reduce over tc bits 0-3 = one head's 16 threads)
  float4 av = *(const float4*)&as1g[c0];
  float4 dv = *(const float4*)&ad1g[c0];
  float ps[8], pd[8];
#pragma unroll
  for (int r = 0; r < 8; ++r) {
    ps[r] = acc[r][0] * av.x + acc[r][1] * av.y + acc[r][2] * av.z + acc[r][3] * av.w;
    pd[r] = acc[r][0] * dv.x + acc[r][1] * dv.y + acc[r][2] * dv.z + acc[r][3] * dv.w;
  }
#pragma unroll
  for (int o = 1; o <= 8; o <<= 1) {
#pragma unroll
    for (int r = 0; r < 8; ++r) {
      ps[r] += __shfl_xor(ps[r], o);
      pd[r] += __shfl_xor(pd[r], o);
    }
  }
  if (tc == 0 || tc == 16) {
    int hh = tc >> 4;
#pragma unroll
    for (int r = 0; r < 8; ++r) {
      a1s[row[r] * 2 + hh] = ps[r];
      a1d[row[r] * 2 + hh] = pd[r];
    }
  }
}

// ---------- CSR build (in-edges only; self-loop "+1" folded into scans) ----------
__global__ void k_hist(const int* __restrict__ ei, int* __restrict__ deg) {
  int t4 = blockIdx.x * 256 + threadIdx.x;
  if (t4 >= NE / 4) return;
  int4 d = *(const int4*)&ei[NE + t4 * 4];
  atomicAdd(&deg[d.x], 1);
  atomicAdd(&deg[d.y], 1);
  atomicAdd(&deg[d.z], 1);
  atomicAdd(&deg[d.w], 1);
}

__global__ void k_scan1(const int* __restrict__ deg, int* __restrict__ bsum) {
  __shared__ int lds[256];
  int t = threadIdx.x;
  int base = blockIdx.x * 1024 + t * 4;
  int s = 0;
  for (int j = 0; j < 4; ++j) { int i = base + j; s += (i < NN) ? (deg[i] + 1) : 0; }
  lds[t] = s; __syncthreads();
  for (int o = 128; o > 0; o >>= 1) { if (t < o) lds[t] += lds[t + o]; __syncthreads(); }
  if (t == 0) bsum[blockIdx.x] = lds[0];
}

__global__ void k_scan2(int* __restrict__ bsum, int nb) {
  __shared__ int lds[128];
  int t = threadIdx.x;
  int v = (t < nb) ? bsum[t] : 0;
  lds[t] = v; __syncthreads();
  for (int o = 1; o < 128; o <<= 1) {
    int u = (t >= o) ? lds[t - o] : 0;
    __syncthreads();
    lds[t] += u;
    __syncthreads();
  }
  if (t < nb) bsum[t] = lds[t] - v;   // exclusive
}

__global__ void k_scan3(const int* __restrict__ deg, const int* __restrict__ bbase,
                        int* __restrict__ rowptr, int* __restrict__ cursor) {
  __shared__ int lds[256];
  int t = threadIdx.x;
  int base = blockIdx.x * 1024 + t * 4;
  int v[4]; int s = 0;
  for (int j = 0; j < 4; ++j) { int i = base + j; v[j] = (i < NN) ? (deg[i] + 1) : 0; s += v[j]; }
  lds[t] = s; __syncthreads();
  for (int o = 1; o < 256; o <<= 1) {
    int u = (t >= o) ? lds[t - o] : 0;
    __syncthreads();
    lds[t] += u;
    __syncthreads();
  }
  int excl = lds[t] - s + bbase[blockIdx.x];
  for (int j = 0; j < 4; ++j) {
    int i = base + j;
    if (i <= NN) {
      rowptr[i] = excl;
      if (i < NN) cursor[i] = excl;
    }
    excl += v[j];
  }
}

// ---------- scatter edges into CSR, packing (exp0, exp1, src, ez) per slot ----------
// 4 edges/thread (vectorized ei/ef loads); self-loops in the tail thread range.
__global__ void k_scatter(const int* __restrict__ ei, const float* __restrict__ ef,
                          const float* __restrict__ a1s, const float* __restrict__ a1d,
                          const float* __restrict__ q, int* __restrict__ cursor,
                          float4* __restrict__ cpk) {
  int t4 = blockIdx.x * 256 + threadIdx.x;
  const int NT_E = NE / 4;                 // 400000
  if (t4 < NT_E) {
    int e0 = t4 * 4;
    int4 ss = *(const int4*)&ei[e0];
    int4 dd = *(const int4*)&ei[NE + e0];
    float4 fA = *(const float4*)&ef[e0 * 3];
    float4 fB = *(const float4*)&ef[e0 * 3 + 4];
    float4 fC = *(const float4*)&ef[e0 * 3 + 8];
    float f[4][3] = {{fA.x, fA.y, fA.z}, {fA.w, fB.x, fB.y},
                     {fB.z, fB.w, fC.x}, {fC.y, fC.z, fC.w}};
    int src[4] = {ss.x, ss.y, ss.z, ss.w};
    int dst[4] = {dd.x, dd.y, dd.z, dd.w};
#pragma unroll
    for (int j = 0; j < 4; ++j) {
      float e0h = f[j][0] * q[0] + f[j][1] * q[2] + f[j][2] * q[4];
      float e1h = f[j][0] * q[1] + f[j][1] * q[3] + f[j][2] * q[5];
      float ez  = f[j][0] * q[8] + f[j][1] * q[9] + f[j][2] * q[10];
      float al0 = a1s[src[j] * 2] + a1d[dst[j] * 2] + e0h;
      float al1 = a1s[src[j] * 2 + 1] + a1d[dst[j] * 2 + 1] + e1h;
      al0 = al0 > 0.f ? al0 : NEG_SLOPE * al0;
      al1 = al1 > 0.f ? al1 : NEG_SLOPE * al1;
      int pos = atomicAdd(&cursor[dst[j]], 1);
      float4 pk;
      pk.x = __expf(al0); pk.y = __expf(al1);
      pk.z = __int_as_float(src[j]); pk.w = ez;
      cpk[pos] = pk;
    }
  } else if (t4 < NT_E + NN) {
    int n = t4 - NT_E;                     // self-loop, zero edge_attr
    float al0 = a1s[n * 2] + a1d[n * 2];
    float al1 = a1s[n * 2 + 1] + a1d[n * 2 + 1];
    al0 = al0 > 0.f ? al0 : NEG_SLOPE * al0;
    al1 = al1 > 0.f ? al1 : NEG_SLOPE * al1;
    int pos = atomicAdd(&cursor[n], 1);
    float4 pk;
    pk.x = __expf(al0); pk.y = __expf(al1);
    pk.z = __int_as_float(n); pk.w = 0.f;
    cpk[pos] = pk;
  }
}

// ---------- layer1 aggregation + bias + ELU + layer2 projection epilogue ----------
// one wave per dst node; 16-lane granules: granule g (lane>>4) owns edge i+g,
// lane-in-granule lp owns channels 8lp..8lp+7 (one uint4 = 16B of the bf16 row).
// head0 = lp<8, head1 = lp>=8. Tail via clamp + zero weight (no scalar tail).
// Unroll x2 -> 4 independent VMEM in flight. Cross-granule combine: shfl_xor 16/32.
__global__ __launch_bounds__(256) void k_agg1(const unsigned short* __restrict__ h1b,
                                              const int* __restrict__ rowptr,
                                              const float4* __restrict__ cpk,
                                              const float* __restrict__ b1,
                                              const float* __restrict__ W2,
                                              const float* __restrict__ as2,
                                              const float* __restrict__ ad2,
                                              float* __restrict__ h2,
                                              float* __restrict__ a2s, float* __restrict__ a2d) {
  int n = (int)((blockIdx.x * 256 + threadIdx.x) >> 6);
  int lane = threadIdx.x & 63;
  if (n >= NN) return;
  int s0 = rowptr[n], s1 = rowptr[n + 1];
  int g = lane >> 4;            // granule 0..3
  int lp = lane & 15;           // channel group: 8lp..8lp+7
  bool head1 = lp >= 8;
  int slast = s1 - 1;

  float acc[8];
#pragma unroll
  for (int j = 0; j < 8; ++j) acc[j] = 0.f;
  float den = 0.f;

  for (int i = s0; i < s1; i += 8) {
    int iA = i + g, iB = i + 4 + g;
    int cA = iA < slast ? iA : slast;
    int cB = iB < slast ? iB : slast;
    float4 pA = cpk[cA];
    float4 pB = cpk[cB];
    const uint4* rA = (const uint4*)(h1b + ((size_t)__float_as_int(pA.z) << 7)) + lp;
    const uint4* rB = (const uint4*)(h1b + ((size_t)__float_as_int(pB.z) << 7)) + lp;
    uint4 vA = *rA;
    uint4 vB = *rB;
    float eA = head1 ? pA.y : pA.x;
    float eB = head1 ? pB.y : pB.x;
    eA = (iA < s1) ? eA : 0.f;
    eB = (iB < s1) ? eB : 0.f;
    den += eA + eB;
    acc[0] += eA * blo(vA.x) + eB * blo(vB.x);
    acc[1] += eA * bhi(vA.x) + eB * bhi(vB.x);
    acc[2] += eA * blo(vA.y) + eB * blo(vB.y);
    acc[3] += eA * bhi(vA.y) + eB * bhi(vB.y);
    acc[4] += eA * blo(vA.z) + eB * blo(vB.z);
    acc[5] += eA * bhi(vA.z) + eB * bhi(vB.z);
    acc[6] += eA * blo(vA.w) + eB * blo(vB.w);
    acc[7] += eA * bhi(vA.w) + eB * bhi(vB.w);
  }
  // combine the 4 granule partials (lane bits 4,5)
#pragma unroll
  for (int o = 16; o <= 32; o <<= 1) {
    den += __shfl_xor(den, o);
#pragma unroll
    for (int j = 0; j < 8; ++j) acc[j] += __shfl_xor(acc[j], o);
  }
  // epilogue: channels 8lp..8lp+7
  float4 bA = *(const float4*)&b1[lp * 8];
  float4 bB = *(const float4*)&b1[lp * 8 + 4];
  float bb[8] = {bA.x, bA.y, bA.z, bA.w, bB.x, bB.y, bB.z, bB.w};
  float inv = 1.f / (den + GEPS);
  float r[8];
#pragma unroll
  for (int j = 0; j < 8; ++j) {
    float v = acc[j] * inv + bb[j];
    r[j] = v > 0.f ? v : __expf(v) - 1.f;   // ELU
  }
  // layer2 projection: W2 rows 8lp..8lp+7 (16 floats at W2+16lp)
  float4 wA = *(const float4*)&W2[lp * 16];
  float4 wB = *(const float4*)&W2[lp * 16 + 4];
  float4 wC = *(const float4*)&W2[lp * 16 + 8];
  float4 wD = *(const float4*)&W2[lp * 16 + 12];
  float p20 = r[0] * wA.x + r[1] * wA.z + r[2] * wB.x + r[3] * wB.z
            + r[4] * wC.x + r[5] * wC.z + r[6] * wD.x + r[7] * wD.z;
  float p21 = r[0] * wA.y + r[1] * wA.w + r[2] * wB.y + r[3] * wB.w
            + r[4] * wC.y + r[5] * wC.w + r[6] * wD.y + r[7] * wD.w;
#pragma unroll
  for (int o = 1; o <= 8; o <<= 1) { p20 += __shfl_xor(p20, o); p21 += __shfl_xor(p21, o); }
  if (lane == 0) {
    h2[n * 2] = p20; h2[n * 2 + 1] = p21;
    a2s[n] = p20 * as2[0] + p21 * as2[1];
    a2d[n] = p20 * ad2[0] + p21 * ad2[1];
  }
}

// ---------- layer2 aggregation (lane-parallel; tiny channels; no max pass) ----------
__global__ __launch_bounds__(256) void k_agg2(const int* __restrict__ rowptr,
                                              const float4* __restrict__ cpk,
                                              const float* __restrict__ h2,
                                              const float* __restrict__ a2s,
                                              const float* __restrict__ a2d,
                                              const float* __restrict__ b2,
                                              float* __restrict__ out) {
  int n = (int)((blockIdx.x * 256 + threadIdx.x) >> 6);
  int lane = threadIdx.x & 63;
  if (n >= NN) return;
  int s0 = rowptr[n], s1 = rowptr[n + 1];
  float adn = a2d[n];
  const float2* h2v = (const float2*)h2;
  float den = 0.f, acc0 = 0.f, acc1 = 0.f;
  for (int i = s0 + lane; i < s1; i += 64) {
    float4 pk = cpk[i];
    int s = __float_as_int(pk.z);
    float v = a2s[s] + adn + pk.w;
    v = v > 0.f ? v : NEG_SLOPE * v;
    float p = __expf(v);
    float2 hv = h2v[s];
    den += p;
    acc0 += p * hv.x;
    acc1 += p * hv.y;
  }
  for (int o = 32; o > 0; o >>= 1) {
    den += __shfl_xor(den, o);
    acc0 += __shfl_xor(acc0, o);
    acc1 += __shfl_xor(acc1, o);
  }
  if (lane == 0) {
    out[n * 2] = acc0 / (den + GEPS) + b2[0];
    out[n * 2 + 1] = acc1 / (den + GEPS) + b2[1];
  }
}

extern "C" void kernel_launch(void* const* d_in, const int* in_sizes, int n_in,
                              void* d_out, int out_size, void* d_ws, size_t ws_size,
                              hipStream_t stream) {
  (void)in_sizes; (void)n_in; (void)out_size; (void)ws_size;
  const float* x   = (const float*)d_in[0];
  const int*   ei  = (const int*)d_in[1];
  const float* ef  = (const float*)d_in[2];
  const float* W1  = (const float*)d_in[3];
  const float* as1 = (const float*)d_in[5];
  const float* ad1 = (const float*)d_in[6];
  const float* b1  = (const float*)d_in[8];
  const float* W2  = (const float*)d_in[9];
  const float* as2 = (const float*)d_in[11];
  const float* ad2 = (const float*)d_in[12];
  const float* b2  = (const float*)d_in[14];
  const float* We1 = (const float*)d_in[4];
  const float* ae1 = (const float*)d_in[7];
  const float* We2 = (const float*)d_in[10];
  const float* ae2 = (const float*)d_in[13];
  float* out = (float*)d_out;

  char* w = (char*)d_ws;
  auto alloc = [&](size_t bytes) -> char* {
    char* p = w; w += (bytes + 255) & ~(size_t)255; return p;
  };
  unsigned short* h1b = (unsigned short*)alloc((size_t)NN * 128 * 2);  // 25.6 MB
  float*  a1s    = (float*)alloc((size_t)NN * 2 * 4);
  float*  a1d    = (float*)alloc((size_t)NN * 2 * 4);
  float*  h2     = (float*)alloc((size_t)NN * 2 * 4);
  float*  a2s    = (float*)alloc((size_t)NN * 4);
  float*  a2d    = (float*)alloc((size_t)NN * 4);
  float*  q      = (float*)alloc(64);
  int*    deg    = (int*)alloc((size_t)NN * 4);
  int*    rowptr = (int*)alloc((size_t)(NN + 1) * 4);
  int*    cursor = (int*)alloc((size_t)NN * 4);
  int*    bsum   = (int*)alloc(128 * 4);
  float4* cpk    = (float4*)alloc((size_t)E2 * 16);       // 27.2 MB

  const int NB_SCAN = (NN + 1023) / 1024;                 // 98

  hipLaunchKernelGGL(k_prep, dim3(1), dim3(16), 0, stream, We1, ae1, We2, ae2, q);
  hipLaunchKernelGGL(k_gemm, dim3((NN + 127) / 128), dim3(512), 0, stream,
                     x, W1, as1, ad1, h1b, a1s, a1d);
  hipMemsetAsync(deg, 0, (size_t)NN * 4, stream);
  hipLaunchKernelGGL(k_hist, dim3((NE / 4 + 255) / 256), dim3(256), 0, stream, ei, deg);
  hipLaunchKernelGGL(k_scan1, dim3(NB_SCAN), dim3(256), 0, stream, deg, bsum);
  hipLaunchKernelGGL(k_scan2, dim3(1), dim3(128), 0, stream, bsum, NB_SCAN);
  hipLaunchKernelGGL(k_scan3, dim3(NB_SCAN), dim3(256), 0, stream, deg, bsum, rowptr, cursor);
  hipLaunchKernelGGL(k_scatter, dim3(((NE / 4 + NN) + 255) / 256), dim3(256), 0, stream,
                     ei, ef, a1s, a1d, q, cursor, cpk);
  hipLaunchKernelGGL(k_agg1, dim3((NN * 64 + 255) / 256), dim3(256), 0, stream,
                     h1b, rowptr, cpk, b1, W2, as2, ad2, h2, a2s, a2d);
  hipLaunchKernelGGL(k_agg2, dim3((NN * 64 + 255) / 256), dim3(256), 0, stream,
                     rowptr, cpk, h2, a2s, a2d, b2, out);
}

// Round 6
// 424.078 us; speedup vs baseline: 1.4164x; 1.0659x over previous
//
#include <hip/hip_runtime.h>
#include <hip/hip_bf16.h>

#define NN 100000
#define NE 1600000
#define E2 (NE + NN)          // edges + self loops
#define NEG_SLOPE 0.2f
#define GEPS 1e-16f

// fp32 -> bf16 round-to-nearest-even
__device__ __forceinline__ unsigned short f2b(float f) {
  unsigned u = __float_as_uint(f);
  u += 0x7fffu + ((u >> 16) & 1u);
  return (unsigned short)(u >> 16);
}
__device__ __forceinline__ float blo(unsigned u) { return __uint_as_float(u << 16); }
__device__ __forceinline__ float bhi(unsigned u) { return __uint_as_float(u & 0xffff0000u); }

// ---------- tiny prep: q1[3][2] (layer1 edge-att vector), q2[3] (layer2) ----------
__global__ void k_prep(const float* __restrict__ We1, const float* __restrict__ ae1,
                       const float* __restrict__ We2, const float* __restrict__ ae2,
                       float* __restrict__ q) {
  int t = threadIdx.x;
  if (t < 6) {
    int d = t >> 1, hh = t & 1;
    float s = 0.f;
    for (int c = 0; c < 64; ++c) s += We1[d * 128 + hh * 64 + c] * ae1[hh * 64 + c];
    q[t] = s;
  } else if (t < 9) {
    int d = t - 6;
    q[8 + d] = We2[d * 2 + 0] * ae2[0] + We2[d * 2 + 1] * ae2[1];
  }
}

// ---------- layer1 GEMM + fused attn scalars ----------
// W1 fully in LDS (64KB). 512 thr, 128 rows/block, 8x4 tile.
// __launch_bounds__(512,4): cap VGPR<=128 -> 2 blocks/CU = 16 waves.
__global__ __launch_bounds__(512, 4) void k_gemm(const float* __restrict__ x,
                                                 const float* __restrict__ W,
                                                 const float* __restrict__ as1g,
                                                 const float* __restrict__ ad1g,
                                                 unsigned short* __restrict__ h1b,
                                                 float* __restrict__ a1s,
                                                 float* __restrict__ a1d) {
  __shared__ float ws[128 * 128];
  int t = threadIdx.x;
  for (int i = t * 4; i < 128 * 128; i += 2048)
    *(float4*)&ws[i] = *(const float4*)&W[i];
  __syncthreads();
  int tc = t & 31, tr = t >> 5;
  int c0 = tc * 4;
  int r0 = blockIdx.x * 128 + tr * 8;
  int row[8];
#pragma unroll
  for (int r = 0; r < 8; ++r) { int rr = r0 + r; row[r] = rr < NN ? rr : NN - 1; }

  float acc[8][4];
#pragma unroll
  for (int r = 0; r < 8; ++r)
#pragma unroll
    for (int c = 0; c < 4; ++c) acc[r][c] = 0.f;

  for (int kk = 0; kk < 128; kk += 4) {
    float4 wv0 = *(const float4*)&ws[(kk + 0) * 128 + c0];
    float4 wv1 = *(const float4*)&ws[(kk + 1) * 128 + c0];
    float4 wv2 = *(const float4*)&ws[(kk + 2) * 128 + c0];
    float4 wv3 = *(const float4*)&ws[(kk + 3) * 128 + c0];
#pragma unroll
    for (int half = 0; half < 2; ++half) {
      float4 xv[4];
#pragma unroll
      for (int r = 0; r < 4; ++r)
        xv[r] = *(const float4*)&x[(size_t)row[half * 4 + r] * 128 + kk];
#pragma unroll
      for (int r = 0; r < 4; ++r) {
        int rr = half * 4 + r;
        acc[rr][0] += xv[r].x * wv0.x + xv[r].y * wv1.x + xv[r].z * wv2.x + xv[r].w * wv3.x;
        acc[rr][1] += xv[r].x * wv0.y + xv[r].y * wv1.y + xv[r].z * wv2.y + xv[r].w * wv3.y;
        acc[rr][2] += xv[r].x * wv0.z + xv[r].y * wv1.z + xv[r].z * wv2.z + xv[r].w * wv3.z;
        acc[rr][3] += xv[r].x * wv0.w + xv[r].y * wv1.w + xv[r].z * wv2.w + xv[r].w * wv3.w;
      }
    }
  }
#pragma unroll
  for (int r = 0; r < 8; ++r) {
    uint2 st;
    st.x = (unsigned)f2b(acc[r][0]) | ((unsigned)f2b(acc[r][1]) << 16);
    st.y = (unsigned)f2b(acc[r][2]) | ((unsigned)f2b(acc[r][3]) << 16);
    *(uint2*)&h1b[(size_t)row[r] * 128 + c0] = st;
  }
  float4 av = *(const float4*)&as1g[c0];
  float4 dv = *(const float4*)&ad1g[c0];
  float ps[8], pd[8];
#pragma unroll
  for (int r = 0; r < 8; ++r) {
    ps[r] = acc[r][0] * av.x + acc[r][1] * av.y + acc[r][2] * av.z + acc[r][3] * av.w;
    pd[r] = acc[r][0] * dv.x + acc[r][1] * dv.y + acc[r][2] * dv.z + acc[r][3] * dv.w;
  }
#pragma unroll
  for (int o = 1; o <= 8; o <<= 1) {
#pragma unroll
    for (int r = 0; r < 8; ++r) {
      ps[r] += __shfl_xor(ps[r], o);
      pd[r] += __shfl_xor(pd[r], o);
    }
  }
  if (tc == 0 || tc == 16) {
    int hh = tc >> 4;
#pragma unroll
    for (int r = 0; r < 8; ++r) {
      a1s[row[r] * 2 + hh] = ps[r];
      a1d[row[r] * 2 + hh] = pd[r];
    }
  }
}

// ---------- CSR build: histogram + per-edge rank (the ONLY atomic pass) ----------
__global__ void k_hist(const int* __restrict__ ei, int* __restrict__ deg,
                       int* __restrict__ rank) {
  int t4 = blockIdx.x * 256 + threadIdx.x;
  if (t4 >= NE / 4) return;
  int4 d = *(const int4*)&ei[NE + t4 * 4];
  int4 rk;
  rk.x = atomicAdd(&deg[d.x], 1);
  rk.y = atomicAdd(&deg[d.y], 1);
  rk.z = atomicAdd(&deg[d.z], 1);
  rk.w = atomicAdd(&deg[d.w], 1);
  *(int4*)&rank[t4 * 4] = rk;
}

__global__ void k_scan1(const int* __restrict__ deg, int* __restrict__ bsum) {
  __shared__ int lds[256];
  int t = threadIdx.x;
  int base = blockIdx.x * 1024 + t * 4;
  int s = 0;
  for (int j = 0; j < 4; ++j) { int i = base + j; s += (i < NN) ? (deg[i] + 1) : 0; }
  lds[t] = s; __syncthreads();
  for (int o = 128; o > 0; o >>= 1) { if (t < o) lds[t] += lds[t + o]; __syncthreads(); }
  if (t == 0) bsum[blockIdx.x] = lds[0];
}

__global__ void k_scan2(int* __restrict__ bsum, int nb) {
  __shared__ int lds[128];
  int t = threadIdx.x;
  int v = (t < nb) ? bsum[t] : 0;
  lds[t] = v; __syncthreads();
  for (int o = 1; o < 128; o <<= 1) {
    int u = (t >= o) ? lds[t - o] : 0;
    __syncthreads();
    lds[t] += u;
    __syncthreads();
  }
  if (t < nb) bsum[t] = lds[t] - v;   // exclusive
}

// scan3 also writes each node's self-loop packet at slot 0 (pos = rowptr[n]):
// src=dst=n, edge_attr=0 -> alpha = a1s[n]+a1d[n], ez = 0.
__global__ void k_scan3(const int* __restrict__ deg, const int* __restrict__ bbase,
                        const float* __restrict__ a1s, const float* __restrict__ a1d,
                        int* __restrict__ rowptr, float4* __restrict__ cpk) {
  __shared__ int lds[256];
  int t = threadIdx.x;
  int base = blockIdx.x * 1024 + t * 4;
  int v[4]; int s = 0;
  for (int j = 0; j < 4; ++j) { int i = base + j; v[j] = (i < NN) ? (deg[i] + 1) : 0; s += v[j]; }
  lds[t] = s; __syncthreads();
  for (int o = 1; o < 256; o <<= 1) {
    int u = (t >= o) ? lds[t - o] : 0;
    __syncthreads();
    lds[t] += u;
    __syncthreads();
  }
  int excl = lds[t] - s + bbase[blockIdx.x];
  for (int j = 0; j < 4; ++j) {
    int i = base + j;
    if (i <= NN) rowptr[i] = excl;
    if (i < NN) {
      float al0 = a1s[i * 2] + a1d[i * 2];
      float al1 = a1s[i * 2 + 1] + a1d[i * 2 + 1];
      al0 = al0 > 0.f ? al0 : NEG_SLOPE * al0;
      al1 = al1 > 0.f ? al1 : NEG_SLOPE * al1;
      float4 pk;
      pk.x = __expf(al0); pk.y = __expf(al1);
      pk.z = __int_as_float(i); pk.w = 0.f;
      cpk[excl] = pk;            // self-loop at slot 0 of node i's segment
    }
    excl += v[j];
  }
}

// ---------- scatter edges into CSR: NO atomics (pos = rowptr[dst]+1+rank[e]) ----------
// Stores are fully independent -> deep memory-level parallelism.
__global__ void k_scatter(const int* __restrict__ ei, const float* __restrict__ ef,
                          const float* __restrict__ a1s, const float* __restrict__ a1d,
                          const float* __restrict__ q, const int* __restrict__ rowptr,
                          const int* __restrict__ rank, float4* __restrict__ cpk) {
  int t4 = blockIdx.x * 256 + threadIdx.x;
  if (t4 >= NE / 4) return;
  int e0 = t4 * 4;
  int4 ss = *(const int4*)&ei[e0];
  int4 dd = *(const int4*)&ei[NE + e0];
  int4 rk = *(const int4*)&rank[e0];
  float4 fA = *(const float4*)&ef[e0 * 3];
  float4 fB = *(const float4*)&ef[e0 * 3 + 4];
  float4 fC = *(const float4*)&ef[e0 * 3 + 8];
  float f[4][3] = {{fA.x, fA.y, fA.z}, {fA.w, fB.x, fB.y},
                   {fB.z, fB.w, fC.x}, {fC.y, fC.z, fC.w}};
  int src[4] = {ss.x, ss.y, ss.z, ss.w};
  int dst[4] = {dd.x, dd.y, dd.z, dd.w};
  int rnk[4] = {rk.x, rk.y, rk.z, rk.w};
#pragma unroll
  for (int j = 0; j < 4; ++j) {
    float e0h = f[j][0] * q[0] + f[j][1] * q[2] + f[j][2] * q[4];
    float e1h = f[j][0] * q[1] + f[j][1] * q[3] + f[j][2] * q[5];
    float ez  = f[j][0] * q[8] + f[j][1] * q[9] + f[j][2] * q[10];
    float al0 = a1s[src[j] * 2] + a1d[dst[j] * 2] + e0h;
    float al1 = a1s[src[j] * 2 + 1] + a1d[dst[j] * 2 + 1] + e1h;
    al0 = al0 > 0.f ? al0 : NEG_SLOPE * al0;
    al1 = al1 > 0.f ? al1 : NEG_SLOPE * al1;
    int pos = rowptr[dst[j]] + 1 + rnk[j];
    float4 pk;
    pk.x = __expf(al0); pk.y = __expf(al1);
    pk.z = __int_as_float(src[j]); pk.w = ez;
    cpk[pos] = pk;
  }
}

// ---------- layer1 aggregation + bias + ELU + layer2 projection epilogue ----------
// one wave per dst node; 16-lane granules: granule g owns edge i+g, lane lp owns
// channels 8lp..8lp+7 (uint4 of bf16). Tail via clamp + zero weight.
__global__ __launch_bounds__(256) void k_agg1(const unsigned short* __restrict__ h1b,
                                              const int* __restrict__ rowptr,
                                              const float4* __restrict__ cpk,
                                              const float* __restrict__ b1,
                                              const float* __restrict__ W2,
                                              const float* __restrict__ as2,
                                              const float* __restrict__ ad2,
                                              float* __restrict__ h2,
                                              float* __restrict__ a2s, float* __restrict__ a2d) {
  int n = (int)((blockIdx.x * 256 + threadIdx.x) >> 6);
  int lane = threadIdx.x & 63;
  if (n >= NN) return;
  int s0 = rowptr[n], s1 = rowptr[n + 1];
  int g = lane >> 4;
  int lp = lane & 15;
  bool head1 = lp >= 8;
  int slast = s1 - 1;

  float acc[8];
#pragma unroll
  for (int j = 0; j < 8; ++j) acc[j] = 0.f;
  float den = 0.f;

  for (int i = s0; i < s1; i += 8) {
    int iA = i + g, iB = i + 4 + g;
    int cA = iA < slast ? iA : slast;
    int cB = iB < slast ? iB : slast;
    float4 pA = cpk[cA];
    float4 pB = cpk[cB];
    const uint4* rA = (const uint4*)(h1b + ((size_t)__float_as_int(pA.z) << 7)) + lp;
    const uint4* rB = (const uint4*)(h1b + ((size_t)__float_as_int(pB.z) << 7)) + lp;
    uint4 vA = *rA;
    uint4 vB = *rB;
    float eA = head1 ? pA.y : pA.x;
    float eB = head1 ? pB.y : pB.x;
    eA = (iA < s1) ? eA : 0.f;
    eB = (iB < s1) ? eB : 0.f;
    den += eA + eB;
    acc[0] += eA * blo(vA.x) + eB * blo(vB.x);
    acc[1] += eA * bhi(vA.x) + eB * bhi(vB.x);
    acc[2] += eA * blo(vA.y) + eB * blo(vB.y);
    acc[3] += eA * bhi(vA.y) + eB * bhi(vB.y);
    acc[4] += eA * blo(vA.z) + eB * blo(vB.z);
    acc[5] += eA * bhi(vA.z) + eB * bhi(vB.z);
    acc[6] += eA * blo(vA.w) + eB * blo(vB.w);
    acc[7] += eA * bhi(vA.w) + eB * bhi(vB.w);
  }
#pragma unroll
  for (int o = 16; o <= 32; o <<= 1) {
    den += __shfl_xor(den, o);
#pragma unroll
    for (int j = 0; j < 8; ++j) acc[j] += __shfl_xor(acc[j], o);
  }
  float4 bA = *(const float4*)&b1[lp * 8];
  float4 bB = *(const float4*)&b1[lp * 8 + 4];
  float bb[8] = {bA.x, bA.y, bA.z, bA.w, bB.x, bB.y, bB.z, bB.w};
  float inv = 1.f / (den + GEPS);
  float r[8];
#pragma unroll
  for (int j = 0; j < 8; ++j) {
    float v = acc[j] * inv + bb[j];
    r[j] = v > 0.f ? v : __expf(v) - 1.f;   // ELU
  }
  float4 wA = *(const float4*)&W2[lp * 16];
  float4 wB = *(const float4*)&W2[lp * 16 + 4];
  float4 wC = *(const float4*)&W2[lp * 16 + 8];
  float4 wD = *(const float4*)&W2[lp * 16 + 12];
  float p20 = r[0] * wA.x + r[1] * wA.z + r[2] * wB.x + r[3] * wB.z
            + r[4] * wC.x + r[5] * wC.z + r[6] * wD.x + r[7] * wD.z;
  float p21 = r[0] * wA.y + r[1] * wA.w + r[2] * wB.y + r[3] * wB.w
            + r[4] * wC.y + r[5] * wC.w + r[6] * wD.y + r[7] * wD.w;
#pragma unroll
  for (int o = 1; o <= 8; o <<= 1) { p20 += __shfl_xor(p20, o); p21 += __shfl_xor(p21, o); }
  if (lane == 0) {
    h2[n * 2] = p20; h2[n * 2 + 1] = p21;
    a2s[n] = p20 * as2[0] + p21 * as2[1];
    a2d[n] = p20 * ad2[0] + p21 * ad2[1];
  }
}

// ---------- layer2 aggregation ----------
__global__ __launch_bounds__(256) void k_agg2(const int* __restrict__ rowptr,
                                              const float4* __restrict__ cpk,
                                              const float* __restrict__ h2,
                                              const float* __restrict__ a2s,
                                              const float* __restrict__ a2d,
                                              const float* __restrict__ b2,
                                              float* __restrict__ out) {
  int n = (int)((blockIdx.x * 256 + threadIdx.x) >> 6);
  int lane = threadIdx.x & 63;
  if (n >= NN) return;
  int s0 = rowptr[n], s1 = rowptr[n + 1];
  float adn = a2d[n];
  const float2* h2v = (const float2*)h2;
  float den = 0.f, acc0 = 0.f, acc1 = 0.f;
  for (int i = s0 + lane; i < s1; i += 64) {
    float4 pk = cpk[i];
    int s = __float_as_int(pk.z);
    float v = a2s[s] + adn + pk.w;
    v = v > 0.f ? v : NEG_SLOPE * v;
    float p = __expf(v);
    float2 hv = h2v[s];
    den += p;
    acc0 += p * hv.x;
    acc1 += p * hv.y;
  }
  for (int o = 32; o > 0; o >>= 1) {
    den += __shfl_xor(den, o);
    acc0 += __shfl_xor(acc0, o);
    acc1 += __shfl_xor(acc1, o);
  }
  if (lane == 0) {
    out[n * 2] = acc0 / (den + GEPS) + b2[0];
    out[n * 2 + 1] = acc1 / (den + GEPS) + b2[1];
  }
}

extern "C" void kernel_launch(void* const* d_in, const int* in_sizes, int n_in,
                              void* d_out, int out_size, void* d_ws, size_t ws_size,
                              hipStream_t stream) {
  (void)in_sizes; (void)n_in; (void)out_size; (void)ws_size;
  const float* x   = (const float*)d_in[0];
  const int*   ei  = (const int*)d_in[1];
  const float* ef  = (const float*)d_in[2];
  const float* W1  = (const float*)d_in[3];
  const float* We1 = (const float*)d_in[4];
  const float* as1 = (const float*)d_in[5];
  const float* ad1 = (const float*)d_in[6];
  const float* ae1 = (const float*)d_in[7];
  const float* b1  = (const float*)d_in[8];
  const float* W2  = (const float*)d_in[9];
  const float* We2 = (const float*)d_in[10];
  const float* as2 = (const float*)d_in[11];
  const float* ad2 = (const float*)d_in[12];
  const float* ae2 = (const float*)d_in[13];
  const float* b2  = (const float*)d_in[14];
  float* out = (float*)d_out;

  char* w = (char*)d_ws;
  auto alloc = [&](size_t bytes) -> char* {
    char* p = w; w += (bytes + 255) & ~(size_t)255; return p;
  };
  unsigned short* h1b = (unsigned short*)alloc((size_t)NN * 128 * 2);  // 25.6 MB
  float*  a1s    = (float*)alloc((size_t)NN * 2 * 4);
  float*  a1d    = (float*)alloc((size_t)NN * 2 * 4);
  float*  h2     = (float*)alloc((size_t)NN * 2 * 4);
  float*  a2s    = (float*)alloc((size_t)NN * 4);
  float*  a2d    = (float*)alloc((size_t)NN * 4);
  float*  q      = (float*)alloc(64);
  int*    deg    = (int*)alloc((size_t)NN * 4);
  int*    rowptr = (int*)alloc((size_t)(NN + 1) * 4);
  int*    rank   = (int*)alloc((size_t)NE * 4);           // 6.4 MB
  int*    bsum   = (int*)alloc(128 * 4);
  float4* cpk    = (float4*)alloc((size_t)E2 * 16);       // 27.2 MB

  const int NB_SCAN = (NN + 1023) / 1024;                 // 98

  hipLaunchKernelGGL(k_prep, dim3(1), dim3(16), 0, stream, We1, ae1, We2, ae2, q);
  hipLaunchKernelGGL(k_gemm, dim3((NN + 127) / 128), dim3(512), 0, stream,
                     x, W1, as1, ad1, h1b, a1s, a1d);
  hipMemsetAsync(deg, 0, (size_t)NN * 4, stream);
  hipLaunchKernelGGL(k_hist, dim3((NE / 4 + 255) / 256), dim3(256), 0, stream, ei, deg, rank);
  hipLaunchKernelGGL(k_scan1, dim3(NB_SCAN), dim3(256), 0, stream, deg, bsum);
  hipLaunchKernelGGL(k_scan2, dim3(1), dim3(128), 0, stream, bsum, NB_SCAN);
  hipLaunchKernelGGL(k_scan3, dim3(NB_SCAN), dim3(256), 0, stream,
                     deg, bsum, a1s, a1d, rowptr, cpk);
  hipLaunchKernelGGL(k_scatter, dim3((NE / 4 + 255) / 256), dim3(256), 0, stream,
                     ei, ef, a1s, a1d, q, rowptr, rank, cpk);
  hipLaunchKernelGGL(k_agg1, dim3((NN * 64 + 255) / 256), dim3(256), 0, stream,
                     h1b, rowptr, cpk, b1, W2, as2, ad2, h2, a2s, a2d);
  hipLaunchKernelGGL(k_agg2, dim3((NN * 64 + 255) / 256), dim3(256), 0, stream,
                     rowptr, cpk, h2, a2s, a2d, b2, out);
}

// Round 7
// 401.072 us; speedup vs baseline: 1.4976x; 1.0574x over previous
//
#include <hip/hip_runtime.h>
#include <hip/hip_bf16.h>

#define NN 100000
#define NE 1600000
#define E2 (NE + NN)          // edges + self loops
#define NEG_SLOPE 0.2f
#define GEPS 1e-16f

typedef __attribute__((ext_vector_type(8))) short short8;
typedef __attribute__((ext_vector_type(4))) float f32x4;

// fp32 -> bf16 round-to-nearest-even
__device__ __forceinline__ unsigned short f2b(float f) {
  unsigned u = __float_as_uint(f);
  u += 0x7fffu + ((u >> 16) & 1u);
  return (unsigned short)(u >> 16);
}
__device__ __forceinline__ float blo(unsigned u) { return __uint_as_float(u << 16); }
__device__ __forceinline__ float bhi(unsigned u) { return __uint_as_float(u & 0xffff0000u); }

// ---------- prep: q (edge-att vectors) + pq[k] = (W1@as1, W1@ad1) per head ----------
__global__ void k_prep(const float* __restrict__ We1, const float* __restrict__ ae1,
                       const float* __restrict__ We2, const float* __restrict__ ae2,
                       const float* __restrict__ W1, const float* __restrict__ as1,
                       const float* __restrict__ ad1,
                       float* __restrict__ q, float4* __restrict__ pq) {
  int t = threadIdx.x;
  if (t < 6) {
    int d = t >> 1, hh = t & 1;
    float s = 0.f;
    for (int c = 0; c < 64; ++c) s += We1[d * 128 + hh * 64 + c] * ae1[hh * 64 + c];
    q[t] = s;
  } else if (t < 9) {
    int d = t - 6;
    q[8 + d] = We2[d * 2 + 0] * ae2[0] + We2[d * 2 + 1] * ae2[1];
  }
  if (t < 128) {
    float s0 = 0.f, s1 = 0.f, d0 = 0.f, d1 = 0.f;
    for (int c = 0; c < 64; ++c) {
      float w0 = W1[t * 128 + c], w1 = W1[t * 128 + 64 + c];
      s0 += w0 * as1[c];      s1 += w1 * as1[64 + c];
      d0 += w0 * ad1[c];      d1 += w1 * ad1[64 + c];
    }
    pq[t] = make_float4(s0, s1, d0, d1);
  }
}

// ---------- layer1 GEMM via bf16 MFMA + fused attn scalars from fp32 x ----------
// 512 thr (8 waves), 128 rows/block. LDS: xa[128][128] bf16 + wt[128][128] bf16
// (W^T, n-major) = 64KB -> 2 blocks/CU = 16 waves. XOR swizzle on 8-elem chunks
// (c ^ row&15) makes frag ds_read_b128 2-way-free. Wave w: rows (w&1)*64..+63,
// cols (w>>1)*32..+31 -> 4x2 16x16 tiles, K=128 in 4 MFMA steps.
// a1s/a1d = x·pq computed during staging from fp32 x (exact alpha, no bf16 loss).
__global__ __launch_bounds__(512, 4) void k_gemm(const float* __restrict__ x,
                                                 const float* __restrict__ W,
                                                 const float4* __restrict__ pq,
                                                 unsigned short* __restrict__ h1b,
                                                 float* __restrict__ a1s,
                                                 float* __restrict__ a1d) {
  __shared__ unsigned short xa[128 * 128];
  __shared__ unsigned short wt[128 * 128];
  int t = threadIdx.x;
  int row0 = blockIdx.x * 128;

  // stage W^T (fp32 -> bf16, transposed, swizzled)
  {
    int kr = t >> 2, n0 = (t & 3) * 32;
    const float* wp = &W[kr * 128 + n0];
    int cb = kr >> 3, klo = kr & 7;
#pragma unroll
    for (int j = 0; j < 8; ++j) {
      float4 v = *(const float4*)&wp[j * 4];
      int n = n0 + j * 4;
      wt[(n + 0) * 128 + ((cb ^ ((n + 0) & 15)) * 8) + klo] = f2b(v.x);
      wt[(n + 1) * 128 + ((cb ^ ((n + 1) & 15)) * 8) + klo] = f2b(v.y);
      wt[(n + 2) * 128 + ((cb ^ ((n + 2) & 15)) * 8) + klo] = f2b(v.z);
      wt[(n + 3) * 128 + ((cb ^ ((n + 3) & 15)) * 8) + klo] = f2b(v.w);
    }
  }
  // stage x tile (fp32 -> bf16, swizzled) + alpha-scalar partial dots on fp32 x
  {
    int lrow = t >> 2, qq = t & 3;
    int grow = row0 + lrow; if (grow >= NN) grow = NN - 1;
    const float* xp = &x[(size_t)grow * 128 + qq * 32];
    const float4* pqp = &pq[qq * 32];
    float ps0 = 0.f, ps1 = 0.f, pd0 = 0.f, pd1 = 0.f;
    int sw = lrow & 15;
#pragma unroll
    for (int j = 0; j < 4; ++j) {
      float4 u = *(const float4*)&xp[j * 8];
      float4 v = *(const float4*)&xp[j * 8 + 4];
      float xs[8] = {u.x, u.y, u.z, u.w, v.x, v.y, v.z, v.w};
      short8 sv;
#pragma unroll
      for (int e = 0; e < 8; ++e) {
        float4 pv = pqp[j * 8 + e];
        ps0 += xs[e] * pv.x; ps1 += xs[e] * pv.y;
        pd0 += xs[e] * pv.z; pd1 += xs[e] * pv.w;
        sv[e] = (short)f2b(xs[e]);
      }
      int c = qq * 4 + j;
      *(short8*)&xa[lrow * 128 + ((c ^ sw) * 8)] = sv;
    }
    ps0 += __shfl_xor(ps0, 1); ps0 += __shfl_xor(ps0, 2);
    ps1 += __shfl_xor(ps1, 1); ps1 += __shfl_xor(ps1, 2);
    pd0 += __shfl_xor(pd0, 1); pd0 += __shfl_xor(pd0, 2);
    pd1 += __shfl_xor(pd1, 1); pd1 += __shfl_xor(pd1, 2);
    if (qq == 0) {
      *(float2*)&a1s[grow * 2] = make_float2(ps0, ps1);
      *(float2*)&a1d[grow * 2] = make_float2(pd0, pd1);
    }
  }
  __syncthreads();

  int lane = t & 63, w = t >> 6;
  int m = lane & 15, quad = lane >> 4;
  int wm = (w & 1) * 64, wn = (w >> 1) * 32;
  f32x4 acc[4][2];
#pragma unroll
  for (int mi = 0; mi < 4; ++mi)
#pragma unroll
    for (int ni = 0; ni < 2; ++ni) acc[mi][ni] = (f32x4)(0.f);

#pragma unroll
  for (int kk = 0; kk < 4; ++kk) {
    int c = kk * 4 + quad;
    int co = (c ^ m) * 8;
    short8 a[4], b[2];
#pragma unroll
    for (int mi = 0; mi < 4; ++mi)
      a[mi] = *(const short8*)&xa[(wm + mi * 16 + m) * 128 + co];
#pragma unroll
    for (int ni = 0; ni < 2; ++ni)
      b[ni] = *(const short8*)&wt[(wn + ni * 16 + m) * 128 + co];
#pragma unroll
    for (int mi = 0; mi < 4; ++mi)
#pragma unroll
      for (int ni = 0; ni < 2; ++ni)
        acc[mi][ni] = __builtin_amdgcn_mfma_f32_16x16x32_bf16(a[mi], b[ni], acc[mi][ni], 0, 0, 0);
  }
  // epilogue: C/D layout col=lane&15, row=quad*4+reg
#pragma unroll
  for (int mi = 0; mi < 4; ++mi)
#pragma unroll
    for (int r = 0; r < 4; ++r) {
      int grow = row0 + wm + mi * 16 + quad * 4 + r;
      if (grow >= NN) grow = NN - 1;
#pragma unroll
      for (int ni = 0; ni < 2; ++ni)
        h1b[(size_t)grow * 128 + wn + ni * 16 + m] = f2b(acc[mi][ni][r]);
    }
}

// ---------- CSR build: histogram + per-edge rank (the ONLY atomic pass) ----------
__global__ void k_hist(const int* __restrict__ ei, int* __restrict__ deg,
                       int* __restrict__ rank) {
  int t4 = blockIdx.x * 256 + threadIdx.x;
  if (t4 >= NE / 4) return;
  int4 d = *(const int4*)&ei[NE + t4 * 4];
  int4 rk;
  rk.x = atomicAdd(&deg[d.x], 1);
  rk.y = atomicAdd(&deg[d.y], 1);
  rk.z = atomicAdd(&deg[d.z], 1);
  rk.w = atomicAdd(&deg[d.w], 1);
  *(int4*)&rank[t4 * 4] = rk;
}

__global__ void k_scan1(const int* __restrict__ deg, int* __restrict__ bsum) {
  __shared__ int lds[256];
  int t = threadIdx.x;
  int base = blockIdx.x * 1024 + t * 4;
  int s = 0;
  for (int j = 0; j < 4; ++j) { int i = base + j; s += (i < NN) ? (deg[i] + 1) : 0; }
  lds[t] = s; __syncthreads();
  for (int o = 128; o > 0; o >>= 1) { if (t < o) lds[t] += lds[t + o]; __syncthreads(); }
  if (t == 0) bsum[blockIdx.x] = lds[0];
}

__global__ void k_scan2(int* __restrict__ bsum, int nb) {
  __shared__ int lds[128];
  int t = threadIdx.x;
  int v = (t < nb) ? bsum[t] : 0;
  lds[t] = v; __syncthreads();
  for (int o = 1; o < 128; o <<= 1) {
    int u = (t >= o) ? lds[t - o] : 0;
    __syncthreads();
    lds[t] += u;
    __syncthreads();
  }
  if (t < nb) bsum[t] = lds[t] - v;   // exclusive
}

// scan3 also writes each node's self-loop packet at slot 0 (pos = rowptr[n])
__global__ void k_scan3(const int* __restrict__ deg, const int* __restrict__ bbase,
                        const float* __restrict__ a1s, const float* __restrict__ a1d,
                        int* __restrict__ rowptr, float4* __restrict__ cpk) {
  __shared__ int lds[256];
  int t = threadIdx.x;
  int base = blockIdx.x * 1024 + t * 4;
  int v[4]; int s = 0;
  for (int j = 0; j < 4; ++j) { int i = base + j; v[j] = (i < NN) ? (deg[i] + 1) : 0; s += v[j]; }
  lds[t] = s; __syncthreads();
  for (int o = 1; o < 256; o <<= 1) {
    int u = (t >= o) ? lds[t - o] : 0;
    __syncthreads();
    lds[t] += u;
    __syncthreads();
  }
  int excl = lds[t] - s + bbase[blockIdx.x];
  for (int j = 0; j < 4; ++j) {
    int i = base + j;
    if (i <= NN) rowptr[i] = excl;
    if (i < NN) {
      float al0 = a1s[i * 2] + a1d[i * 2];
      float al1 = a1s[i * 2 + 1] + a1d[i * 2 + 1];
      al0 = al0 > 0.f ? al0 : NEG_SLOPE * al0;
      al1 = al1 > 0.f ? al1 : NEG_SLOPE * al1;
      float4 pk;
      pk.x = __expf(al0); pk.y = __expf(al1);
      pk.z = __int_as_float(i); pk.w = 0.f;
      cpk[excl] = pk;            // self-loop at slot 0 of node i's segment
    }
    excl += v[j];
  }
}

// ---------- scatter edges into CSR: NO atomics (pos = rowptr[dst]+1+rank[e]) ----------
__global__ void k_scatter(const int* __restrict__ ei, const float* __restrict__ ef,
                          const float* __restrict__ a1s, const float* __restrict__ a1d,
                          const float* __restrict__ q, const int* __restrict__ rowptr,
                          const int* __restrict__ rank, float4* __restrict__ cpk) {
  int t4 = blockIdx.x * 256 + threadIdx.x;
  if (t4 >= NE / 4) return;
  int e0 = t4 * 4;
  int4 ss = *(const int4*)&ei[e0];
  int4 dd = *(const int4*)&ei[NE + e0];
  int4 rk = *(const int4*)&rank[e0];
  float4 fA = *(const float4*)&ef[e0 * 3];
  float4 fB = *(const float4*)&ef[e0 * 3 + 4];
  float4 fC = *(const float4*)&ef[e0 * 3 + 8];
  float f[4][3] = {{fA.x, fA.y, fA.z}, {fA.w, fB.x, fB.y},
                   {fB.z, fB.w, fC.x}, {fC.y, fC.z, fC.w}};
  int src[4] = {ss.x, ss.y, ss.z, ss.w};
  int dst[4] = {dd.x, dd.y, dd.z, dd.w};
  int rnk[4] = {rk.x, rk.y, rk.z, rk.w};
#pragma unroll
  for (int j = 0; j < 4; ++j) {
    float e0h = f[j][0] * q[0] + f[j][1] * q[2] + f[j][2] * q[4];
    float e1h = f[j][0] * q[1] + f[j][1] * q[3] + f[j][2] * q[5];
    float ez  = f[j][0] * q[8] + f[j][1] * q[9] + f[j][2] * q[10];
    float al0 = a1s[src[j] * 2] + a1d[dst[j] * 2] + e0h;
    float al1 = a1s[src[j] * 2 + 1] + a1d[dst[j] * 2 + 1] + e1h;
    al0 = al0 > 0.f ? al0 : NEG_SLOPE * al0;
    al1 = al1 > 0.f ? al1 : NEG_SLOPE * al1;
    int pos = rowptr[dst[j]] + 1 + rnk[j];
    float4 pk;
    pk.x = __expf(al0); pk.y = __expf(al1);
    pk.z = __int_as_float(src[j]); pk.w = ez;
    cpk[pos] = pk;
  }
}

// ---------- layer1 aggregation + bias + ELU + layer2 projection epilogue ----------
__global__ __launch_bounds__(256) void k_agg1(const unsigned short* __restrict__ h1b,
                                              const int* __restrict__ rowptr,
                                              const float4* __restrict__ cpk,
                                              const float* __restrict__ b1,
                                              const float* __restrict__ W2,
                                              const float* __restrict__ as2,
                                              const float* __restrict__ ad2,
                                              float* __restrict__ h2,
                                              float* __restrict__ a2s, float* __restrict__ a2d) {
  int n = (int)((blockIdx.x * 256 + threadIdx.x) >> 6);
  int lane = threadIdx.x & 63;
  if (n >= NN) return;
  int s0 = rowptr[n], s1 = rowptr[n + 1];
  int g = lane >> 4;
  int lp = lane & 15;
  bool head1 = lp >= 8;
  int slast = s1 - 1;

  float acc[8];
#pragma unroll
  for (int j = 0; j < 8; ++j) acc[j] = 0.f;
  float den = 0.f;

  for (int i = s0; i < s1; i += 8) {
    int iA = i + g, iB = i + 4 + g;
    int cA = iA < slast ? iA : slast;
    int cB = iB < slast ? iB : slast;
    float4 pA = cpk[cA];
    float4 pB = cpk[cB];
    const uint4* rA = (const uint4*)(h1b + ((size_t)__float_as_int(pA.z) << 7)) + lp;
    const uint4* rB = (const uint4*)(h1b + ((size_t)__float_as_int(pB.z) << 7)) + lp;
    uint4 vA = *rA;
    uint4 vB = *rB;
    float eA = head1 ? pA.y : pA.x;
    float eB = head1 ? pB.y : pB.x;
    eA = (iA < s1) ? eA : 0.f;
    eB = (iB < s1) ? eB : 0.f;
    den += eA + eB;
    acc[0] += eA * blo(vA.x) + eB * blo(vB.x);
    acc[1] += eA * bhi(vA.x) + eB * bhi(vB.x);
    acc[2] += eA * blo(vA.y) + eB * blo(vB.y);
    acc[3] += eA * bhi(vA.y) + eB * bhi(vB.y);
    acc[4] += eA * blo(vA.z) + eB * blo(vB.z);
    acc[5] += eA * bhi(vA.z) + eB * bhi(vB.z);
    acc[6] += eA * blo(vA.w) + eB * blo(vB.w);
    acc[7] += eA * bhi(vA.w) + eB * bhi(vB.w);
  }
#pragma unroll
  for (int o = 16; o <= 32; o <<= 1) {
    den += __shfl_xor(den, o);
#pragma unroll
    for (int j = 0; j < 8; ++j) acc[j] += __shfl_xor(acc[j], o);
  }
  float4 bA = *(const float4*)&b1[lp * 8];
  float4 bB = *(const float4*)&b1[lp * 8 + 4];
  float bb[8] = {bA.x, bA.y, bA.z, bA.w, bB.x, bB.y, bB.z, bB.w};
  float inv = 1.f / (den + GEPS);
  float r[8];
#pragma unroll
  for (int j = 0; j < 8; ++j) {
    float v = acc[j] * inv + bb[j];
    r[j] = v > 0.f ? v : __expf(v) - 1.f;   // ELU
  }
  float4 wA = *(const float4*)&W2[lp * 16];
  float4 wB = *(const float4*)&W2[lp * 16 + 4];
  float4 wC = *(const float4*)&W2[lp * 16 + 8];
  float4 wD = *(const float4*)&W2[lp * 16 + 12];
  float p20 = r[0] * wA.x + r[1] * wA.z + r[2] * wB.x + r[3] * wB.z
            + r[4] * wC.x + r[5] * wC.z + r[6] * wD.x + r[7] * wD.z;
  float p21 = r[0] * wA.y + r[1] * wA.w + r[2] * wB.y + r[3] * wB.w
            + r[4] * wC.y + r[5] * wC.w + r[6] * wD.y + r[7] * wD.w;
#pragma unroll
  for (int o = 1; o <= 8; o <<= 1) { p20 += __shfl_xor(p20, o); p21 += __shfl_xor(p21, o); }
  if (lane == 0) {
    h2[n * 2] = p20; h2[n * 2 + 1] = p21;
    a2s[n] = p20 * as2[0] + p21 * as2[1];
    a2d[n] = p20 * ad2[0] + p21 * ad2[1];
  }
}

// ---------- layer2 aggregation ----------
__global__ __launch_bounds__(256) void k_agg2(const int* __restrict__ rowptr,
                                              const float4* __restrict__ cpk,
                                              const float* __restrict__ h2,
                                              const float* __restrict__ a2s,
                                              const float* __restrict__ a2d,
                                              const float* __restrict__ b2,
                                              float* __restrict__ out) {
  int n = (int)((blockIdx.x * 256 + threadIdx.x) >> 6);
  int lane = threadIdx.x & 63;
  if (n >= NN) return;
  int s0 = rowptr[n], s1 = rowptr[n + 1];
  float adn = a2d[n];
  const float2* h2v = (const float2*)h2;
  float den = 0.f, acc0 = 0.f, acc1 = 0.f;
  for (int i = s0 + lane; i < s1; i += 64) {
    float4 pk = cpk[i];
    int s = __float_as_int(pk.z);
    float v = a2s[s] + adn + pk.w;
    v = v > 0.f ? v : NEG_SLOPE * v;
    float p = __expf(v);
    float2 hv = h2v[s];
    den += p;
    acc0 += p * hv.x;
    acc1 += p * hv.y;
  }
  for (int o = 32; o > 0; o >>= 1) {
    den += __shfl_xor(den, o);
    acc0 += __shfl_xor(acc0, o);
    acc1 += __shfl_xor(acc1, o);
  }
  if (lane == 0) {
    out[n * 2] = acc0 / (den + GEPS) + b2[0];
    out[n * 2 + 1] = acc1 / (den + GEPS) + b2[1];
  }
}

extern "C" void kernel_launch(void* const* d_in, const int* in_sizes, int n_in,
                              void* d_out, int out_size, void* d_ws, size_t ws_size,
                              hipStream_t stream) {
  (void)in_sizes; (void)n_in; (void)out_size; (void)ws_size;
  const float* x   = (const float*)d_in[0];
  const int*   ei  = (const int*)d_in[1];
  const float* ef  = (const float*)d_in[2];
  const float* W1  = (const float*)d_in[3];
  const float* We1 = (const float*)d_in[4];
  const float* as1 = (const float*)d_in[5];
  const float* ad1 = (const float*)d_in[6];
  const float* ae1 = (const float*)d_in[7];
  const float* b1  = (const float*)d_in[8];
  const float* W2  = (const float*)d_in[9];
  const float* We2 = (const float*)d_in[10];
  const float* as2 = (const float*)d_in[11];
  const float* ad2 = (const float*)d_in[12];
  const float* ae2 = (const float*)d_in[13];
  const float* b2  = (const float*)d_in[14];
  float* out = (float*)d_out;

  char* w = (char*)d_ws;
  auto alloc = [&](size_t bytes) -> char* {
    char* p = w; w += (bytes + 255) & ~(size_t)255; return p;
  };
  unsigned short* h1b = (unsigned short*)alloc((size_t)NN * 128 * 2);  // 25.6 MB
  float*  a1s    = (float*)alloc((size_t)NN * 2 * 4);
  float*  a1d    = (float*)alloc((size_t)NN * 2 * 4);
  float*  h2     = (float*)alloc((size_t)NN * 2 * 4);
  float*  a2s    = (float*)alloc((size_t)NN * 4);
  float*  a2d    = (float*)alloc((size_t)NN * 4);
  float*  q      = (float*)alloc(64);
  float4* pq     = (float4*)alloc(128 * 16);
  int*    deg    = (int*)alloc((size_t)NN * 4);
  int*    rowptr = (int*)alloc((size_t)(NN + 1) * 4);
  int*    rank   = (int*)alloc((size_t)NE * 4);           // 6.4 MB
  int*    bsum   = (int*)alloc(128 * 4);
  float4* cpk    = (float4*)alloc((size_t)E2 * 16);       // 27.2 MB

  const int NB_SCAN = (NN + 1023) / 1024;                 // 98

  hipLaunchKernelGGL(k_prep, dim3(1), dim3(128), 0, stream,
                     We1, ae1, We2, ae2, W1, as1, ad1, q, pq);
  hipLaunchKernelGGL(k_gemm, dim3((NN + 127) / 128), dim3(512), 0, stream,
                     x, W1, pq, h1b, a1s, a1d);
  hipMemsetAsync(deg, 0, (size_t)NN * 4, stream);
  hipLaunchKernelGGL(k_hist, dim3((NE / 4 + 255) / 256), dim3(256), 0, stream, ei, deg, rank);
  hipLaunchKernelGGL(k_scan1, dim3(NB_SCAN), dim3(256), 0, stream, deg, bsum);
  hipLaunchKernelGGL(k_scan2, dim3(1), dim3(128), 0, stream, bsum, NB_SCAN);
  hipLaunchKernelGGL(k_scan3, dim3(NB_SCAN), dim3(256), 0, stream,
                     deg, bsum, a1s, a1d, rowptr, cpk);
  hipLaunchKernelGGL(k_scatter, dim3((NE / 4 + 255) / 256), dim3(256), 0, stream,
                     ei, ef, a1s, a1d, q, rowptr, rank, cpk);
  hipLaunchKernelGGL(k_agg1, dim3((NN * 64 + 255) / 256), dim3(256), 0, stream,
                     h1b, rowptr, cpk, b1, W2, as2, ad2, h2, a2s, a2d);
  hipLaunchKernelGGL(k_agg2, dim3((NN * 64 + 255) / 256), dim3(256), 0, stream,
                     rowptr, cpk, h2, a2s, a2d, b2, out);
}

// Round 8
// 388.121 us; speedup vs baseline: 1.5476x; 1.0334x over previous
//
#include <hip/hip_runtime.h>
#include <hip/hip_bf16.h>

#define NN 100000
#define NE 1600000
#define NEG_SLOPE 0.2f
#define GEPS 1e-16f

typedef __attribute__((ext_vector_type(8))) short short8;
typedef __attribute__((ext_vector_type(4))) float f32x4;

// fp32 -> bf16 round-to-nearest-even
__device__ __forceinline__ unsigned short f2b(float f) {
  unsigned u = __float_as_uint(f);
  u += 0x7fffu + ((u >> 16) & 1u);
  return (unsigned short)(u >> 16);
}
__device__ __forceinline__ float blo(unsigned u) { return __uint_as_float(u << 16); }
__device__ __forceinline__ float bhi(unsigned u) { return __uint_as_float(u & 0xffff0000u); }

// ---------- prep: q (edge-att vectors) + pq[k] = (W1@as1, W1@ad1) per head ----------
__global__ void k_prep(const float* __restrict__ We1, const float* __restrict__ ae1,
                       const float* __restrict__ We2, const float* __restrict__ ae2,
                       const float* __restrict__ W1, const float* __restrict__ as1,
                       const float* __restrict__ ad1,
                       float* __restrict__ q, float4* __restrict__ pq) {
  int t = threadIdx.x;
  if (t < 6) {
    int d = t >> 1, hh = t & 1;
    float s = 0.f;
    for (int c = 0; c < 64; ++c) s += We1[d * 128 + hh * 64 + c] * ae1[hh * 64 + c];
    q[t] = s;
  } else if (t < 9) {
    int d = t - 6;
    q[8 + d] = We2[d * 2 + 0] * ae2[0] + We2[d * 2 + 1] * ae2[1];
  }
  if (t < 128) {
    float s0 = 0.f, s1 = 0.f, d0 = 0.f, d1 = 0.f;
    for (int c = 0; c < 64; ++c) {
      float w0 = W1[t * 128 + c], w1 = W1[t * 128 + 64 + c];
      s0 += w0 * as1[c];      s1 += w1 * as1[64 + c];
      d0 += w0 * ad1[c];      d1 += w1 * ad1[64 + c];
    }
    pq[t] = make_float4(s0, s1, d0, d1);
  }
}

// ---------- layer1 GEMM via bf16 MFMA + fused attn scalars from fp32 x ----------
__global__ __launch_bounds__(512, 4) void k_gemm(const float* __restrict__ x,
                                                 const float* __restrict__ W,
                                                 const float4* __restrict__ pq,
                                                 unsigned short* __restrict__ h1b,
                                                 float* __restrict__ a1s,
                                                 float* __restrict__ a1d) {
  __shared__ unsigned short xa[128 * 128];
  __shared__ unsigned short wt[128 * 128];
  int t = threadIdx.x;
  int row0 = blockIdx.x * 128;

  // stage W^T (fp32 -> bf16, transposed, swizzled)
  {
    int kr = t >> 2, n0 = (t & 3) * 32;
    const float* wp = &W[kr * 128 + n0];
    int cb = kr >> 3, klo = kr & 7;
#pragma unroll
    for (int j = 0; j < 8; ++j) {
      float4 v = *(const float4*)&wp[j * 4];
      int n = n0 + j * 4;
      wt[(n + 0) * 128 + ((cb ^ ((n + 0) & 15)) * 8) + klo] = f2b(v.x);
      wt[(n + 1) * 128 + ((cb ^ ((n + 1) & 15)) * 8) + klo] = f2b(v.y);
      wt[(n + 2) * 128 + ((cb ^ ((n + 2) & 15)) * 8) + klo] = f2b(v.z);
      wt[(n + 3) * 128 + ((cb ^ ((n + 3) & 15)) * 8) + klo] = f2b(v.w);
    }
  }
  // stage x tile (fp32 -> bf16, swizzled) + alpha-scalar partial dots on fp32 x
  {
    int lrow = t >> 2, qq = t & 3;
    int grow = row0 + lrow; if (grow >= NN) grow = NN - 1;
    const float* xp = &x[(size_t)grow * 128 + qq * 32];
    const float4* pqp = &pq[qq * 32];
    float ps0 = 0.f, ps1 = 0.f, pd0 = 0.f, pd1 = 0.f;
    int sw = lrow & 15;
#pragma unroll
    for (int j = 0; j < 4; ++j) {
      float4 u = *(const float4*)&xp[j * 8];
      float4 v = *(const float4*)&xp[j * 8 + 4];
      float xs[8] = {u.x, u.y, u.z, u.w, v.x, v.y, v.z, v.w};
      short8 sv;
#pragma unroll
      for (int e = 0; e < 8; ++e) {
        float4 pv = pqp[j * 8 + e];
        ps0 += xs[e] * pv.x; ps1 += xs[e] * pv.y;
        pd0 += xs[e] * pv.z; pd1 += xs[e] * pv.w;
        sv[e] = (short)f2b(xs[e]);
      }
      int c = qq * 4 + j;
      *(short8*)&xa[lrow * 128 + ((c ^ sw) * 8)] = sv;
    }
    ps0 += __shfl_xor(ps0, 1); ps0 += __shfl_xor(ps0, 2);
    ps1 += __shfl_xor(ps1, 1); ps1 += __shfl_xor(ps1, 2);
    pd0 += __shfl_xor(pd0, 1); pd0 += __shfl_xor(pd0, 2);
    pd1 += __shfl_xor(pd1, 1); pd1 += __shfl_xor(pd1, 2);
    if (qq == 0) {
      *(float2*)&a1s[grow * 2] = make_float2(ps0, ps1);
      *(float2*)&a1d[grow * 2] = make_float2(pd0, pd1);
    }
  }
  __syncthreads();

  int lane = t & 63, w = t >> 6;
  int m = lane & 15, quad = lane >> 4;
  int wm = (w & 1) * 64, wn = (w >> 1) * 32;
  f32x4 acc[4][2];
#pragma unroll
  for (int mi = 0; mi < 4; ++mi)
#pragma unroll
    for (int ni = 0; ni < 2; ++ni) acc[mi][ni] = (f32x4)(0.f);

#pragma unroll
  for (int kk = 0; kk < 4; ++kk) {
    int c = kk * 4 + quad;
    int co = (c ^ m) * 8;
    short8 a[4], b[2];
#pragma unroll
    for (int mi = 0; mi < 4; ++mi)
      a[mi] = *(const short8*)&xa[(wm + mi * 16 + m) * 128 + co];
#pragma unroll
    for (int ni = 0; ni < 2; ++ni)
      b[ni] = *(const short8*)&wt[(wn + ni * 16 + m) * 128 + co];
#pragma unroll
    for (int mi = 0; mi < 4; ++mi)
#pragma unroll
      for (int ni = 0; ni < 2; ++ni)
        acc[mi][ni] = __builtin_amdgcn_mfma_f32_16x16x32_bf16(a[mi], b[ni], acc[mi][ni], 0, 0, 0);
  }
#pragma unroll
  for (int mi = 0; mi < 4; ++mi)
#pragma unroll
    for (int r = 0; r < 4; ++r) {
      int grow = row0 + wm + mi * 16 + quad * 4 + r;
      if (grow >= NN) grow = NN - 1;
#pragma unroll
      for (int ni = 0; ni < 2; ++ni)
        h1b[(size_t)grow * 128 + wn + ni * 16 + m] = f2b(acc[mi][ni][r]);
    }
}

// ---------- CSR build: histogram + per-edge rank (the ONLY atomic pass) ----------
__global__ void k_hist(const int* __restrict__ ei, int* __restrict__ deg,
                       int* __restrict__ rank) {
  int t4 = blockIdx.x * 256 + threadIdx.x;
  if (t4 >= NE / 4) return;
  int4 d = *(const int4*)&ei[NE + t4 * 4];
  int4 rk;
  rk.x = atomicAdd(&deg[d.x], 1);
  rk.y = atomicAdd(&deg[d.y], 1);
  rk.z = atomicAdd(&deg[d.z], 1);
  rk.w = atomicAdd(&deg[d.w], 1);
  *(int4*)&rank[t4 * 4] = rk;
}

// padded segment length: (deg+1) rounded up to multiple of 8
__device__ __forceinline__ int padlen(int d) { return (d + 8) & ~7; }

__global__ void k_scan1(const int* __restrict__ deg, int* __restrict__ bsum) {
  __shared__ int lds[256];
  int t = threadIdx.x;
  int base = blockIdx.x * 1024 + t * 4;
  int s = 0;
  for (int j = 0; j < 4; ++j) { int i = base + j; s += (i < NN) ? padlen(deg[i]) : 0; }
  lds[t] = s; __syncthreads();
  for (int o = 128; o > 0; o >>= 1) { if (t < o) lds[t] += lds[t + o]; __syncthreads(); }
  if (t == 0) bsum[blockIdx.x] = lds[0];
}

__global__ void k_scan2(int* __restrict__ bsum, int nb) {
  __shared__ int lds[128];
  int t = threadIdx.x;
  int v = (t < nb) ? bsum[t] : 0;
  lds[t] = v; __syncthreads();
  for (int o = 1; o < 128; o <<= 1) {
    int u = (t >= o) ? lds[t - o] : 0;
    __syncthreads();
    lds[t] += u;
    __syncthreads();
  }
  if (t < nb) bsum[t] = lds[t] - v;   // exclusive
}

// scan3: rowptr (padded), self-loop packet at slot 0, zero-weight pad packets at tail.
// Pad packet: weights 0 (agg1 ignores), ez=-1e30 -> agg2's alpha=-inf -> exp=0.
__global__ void k_scan3(const int* __restrict__ deg, const int* __restrict__ bbase,
                        const float* __restrict__ a1s, const float* __restrict__ a1d,
                        int* __restrict__ rowptr, float4* __restrict__ cpk) {
  __shared__ int lds[256];
  int t = threadIdx.x;
  int base = blockIdx.x * 1024 + t * 4;
  int v[4]; int s = 0;
  for (int j = 0; j < 4; ++j) { int i = base + j; v[j] = (i < NN) ? padlen(deg[i]) : 0; s += v[j]; }
  lds[t] = s; __syncthreads();
  for (int o = 1; o < 256; o <<= 1) {
    int u = (t >= o) ? lds[t - o] : 0;
    __syncthreads();
    lds[t] += u;
    __syncthreads();
  }
  int excl = lds[t] - s + bbase[blockIdx.x];
  for (int j = 0; j < 4; ++j) {
    int i = base + j;
    if (i <= NN) rowptr[i] = excl;
    if (i < NN) {
      float al0 = a1s[i * 2] + a1d[i * 2];
      float al1 = a1s[i * 2 + 1] + a1d[i * 2 + 1];
      al0 = al0 > 0.f ? al0 : NEG_SLOPE * al0;
      al1 = al1 > 0.f ? al1 : NEG_SLOPE * al1;
      float4 pk;
      pk.x = __expf(al0); pk.y = __expf(al1);
      pk.z = __int_as_float(i); pk.w = 0.f;
      cpk[excl] = pk;                       // self-loop at slot 0
      float4 pad;
      pad.x = 0.f; pad.y = 0.f; pad.z = __int_as_float(i); pad.w = -1e30f;
      for (int k = 1 + deg[i]; k < v[j]; ++k) cpk[excl + k] = pad;
    }
    excl += v[j];
  }
}

// ---------- scatter edges into CSR: NO atomics (pos = rowptr[dst]+1+rank[e]) ----------
__global__ void k_scatter(const int* __restrict__ ei, const float* __restrict__ ef,
                          const float* __restrict__ a1s, const float* __restrict__ a1d,
                          const float* __restrict__ q, const int* __restrict__ rowptr,
                          const int* __restrict__ rank, float4* __restrict__ cpk) {
  int t4 = blockIdx.x * 256 + threadIdx.x;
  if (t4 >= NE / 4) return;
  int e0 = t4 * 4;
  int4 ss = *(const int4*)&ei[e0];
  int4 dd = *(const int4*)&ei[NE + e0];
  int4 rk = *(const int4*)&rank[e0];
  float4 fA = *(const float4*)&ef[e0 * 3];
  float4 fB = *(const float4*)&ef[e0 * 3 + 4];
  float4 fC = *(const float4*)&ef[e0 * 3 + 8];
  float f[4][3] = {{fA.x, fA.y, fA.z}, {fA.w, fB.x, fB.y},
                   {fB.z, fB.w, fC.x}, {fC.y, fC.z, fC.w}};
  int src[4] = {ss.x, ss.y, ss.z, ss.w};
  int dst[4] = {dd.x, dd.y, dd.z, dd.w};
  int rnk[4] = {rk.x, rk.y, rk.z, rk.w};
#pragma unroll
  for (int j = 0; j < 4; ++j) {
    float e0h = f[j][0] * q[0] + f[j][1] * q[2] + f[j][2] * q[4];
    float e1h = f[j][0] * q[1] + f[j][1] * q[3] + f[j][2] * q[5];
    float ez  = f[j][0] * q[8] + f[j][1] * q[9] + f[j][2] * q[10];
    float al0 = a1s[src[j] * 2] + a1d[dst[j] * 2] + e0h;
    float al1 = a1s[src[j] * 2 + 1] + a1d[dst[j] * 2 + 1] + e1h;
    al0 = al0 > 0.f ? al0 : NEG_SLOPE * al0;
    al1 = al1 > 0.f ? al1 : NEG_SLOPE * al1;
    int pos = rowptr[dst[j]] + 1 + rnk[j];
    float4 pk;
    pk.x = __expf(al0); pk.y = __expf(al1);
    pk.z = __int_as_float(src[j]); pk.w = ez;
    cpk[pos] = pk;
  }
}

// ---------- layer1 aggregation + bias + ELU + layer2 projection epilogue ----------
// one wave per dst node; segments padded to x8 -> no clamps, no tail logic.
// Main loop 16 edges/iter (8 VMEM in flight), remainder one 8-edge block.
// Epilogue packs (h2x, h2y, a2s, a2d) into nd[n] (one float4).
__global__ __launch_bounds__(256) void k_agg1(const unsigned short* __restrict__ h1b,
                                              const int* __restrict__ rowptr,
                                              const float4* __restrict__ cpk,
                                              const float* __restrict__ b1,
                                              const float* __restrict__ W2,
                                              const float* __restrict__ as2,
                                              const float* __restrict__ ad2,
                                              float4* __restrict__ nd) {
  int n = (int)((blockIdx.x * 256 + threadIdx.x) >> 6);
  int lane = threadIdx.x & 63;
  if (n >= NN) return;
  int s0 = rowptr[n], s1 = rowptr[n + 1];
  int g = lane >> 4;
  int lp = lane & 15;
  bool head1 = lp >= 8;

  float acc[8];
#pragma unroll
  for (int j = 0; j < 8; ++j) acc[j] = 0.f;
  float den = 0.f;

  int i = s0;
  for (; i + 16 <= s1; i += 16) {
    float4 pA = cpk[i + g], pB = cpk[i + 4 + g], pC = cpk[i + 8 + g], pD = cpk[i + 12 + g];
    uint4 vA = *((const uint4*)(h1b + ((size_t)__float_as_int(pA.z) << 7)) + lp);
    uint4 vB = *((const uint4*)(h1b + ((size_t)__float_as_int(pB.z) << 7)) + lp);
    uint4 vC = *((const uint4*)(h1b + ((size_t)__float_as_int(pC.z) << 7)) + lp);
    uint4 vD = *((const uint4*)(h1b + ((size_t)__float_as_int(pD.z) << 7)) + lp);
    float eA = head1 ? pA.y : pA.x;
    float eB = head1 ? pB.y : pB.x;
    float eC = head1 ? pC.y : pC.x;
    float eD = head1 ? pD.y : pD.x;
    den += (eA + eB) + (eC + eD);
    acc[0] += eA * blo(vA.x) + eB * blo(vB.x) + eC * blo(vC.x) + eD * blo(vD.x);
    acc[1] += eA * bhi(vA.x) + eB * bhi(vB.x) + eC * bhi(vC.x) + eD * bhi(vD.x);
    acc[2] += eA * blo(vA.y) + eB * blo(vB.y) + eC * blo(vC.y) + eD * blo(vD.y);
    acc[3] += eA * bhi(vA.y) + eB * bhi(vB.y) + eC * bhi(vC.y) + eD * bhi(vD.y);
    acc[4] += eA * blo(vA.z) + eB * blo(vB.z) + eC * blo(vC.z) + eD * blo(vD.z);
    acc[5] += eA * bhi(vA.z) + eB * bhi(vB.z) + eC * bhi(vC.z) + eD * bhi(vD.z);
    acc[6] += eA * blo(vA.w) + eB * blo(vB.w) + eC * blo(vC.w) + eD * blo(vD.w);
    acc[7] += eA * bhi(vA.w) + eB * bhi(vB.w) + eC * bhi(vC.w) + eD * bhi(vD.w);
  }
  if (i < s1) {                       // exactly one 8-edge block
    float4 pA = cpk[i + g], pB = cpk[i + 4 + g];
    uint4 vA = *((const uint4*)(h1b + ((size_t)__float_as_int(pA.z) << 7)) + lp);
    uint4 vB = *((const uint4*)(h1b + ((size_t)__float_as_int(pB.z) << 7)) + lp);
    float eA = head1 ? pA.y : pA.x;
    float eB = head1 ? pB.y : pB.x;
    den += eA + eB;
    acc[0] += eA * blo(vA.x) + eB * blo(vB.x);
    acc[1] += eA * bhi(vA.x) + eB * bhi(vB.x);
    acc[2] += eA * blo(vA.y) + eB * blo(vB.y);
    acc[3] += eA * bhi(vA.y) + eB * bhi(vB.y);
    acc[4] += eA * blo(vA.z) + eB * blo(vB.z);
    acc[5] += eA * bhi(vA.z) + eB * bhi(vB.z);
    acc[6] += eA * blo(vA.w) + eB * blo(vB.w);
    acc[7] += eA * bhi(vA.w) + eB * bhi(vB.w);
  }
#pragma unroll
  for (int o = 16; o <= 32; o <<= 1) {
    den += __shfl_xor(den, o);
#pragma unroll
    for (int j = 0; j < 8; ++j) acc[j] += __shfl_xor(acc[j], o);
  }
  float4 bA = *(const float4*)&b1[lp * 8];
  float4 bB = *(const float4*)&b1[lp * 8 + 4];
  float bb[8] = {bA.x, bA.y, bA.z, bA.w, bB.x, bB.y, bB.z, bB.w};
  float inv = 1.f / (den + GEPS);
  float r[8];
#pragma unroll
  for (int j = 0; j < 8; ++j) {
    float v = acc[j] * inv + bb[j];
    r[j] = v > 0.f ? v : __expf(v) - 1.f;   // ELU
  }
  float4 wA = *(const float4*)&W2[lp * 16];
  float4 wB = *(const float4*)&W2[lp * 16 + 4];
  float4 wC = *(const float4*)&W2[lp * 16 + 8];
  float4 wD = *(const float4*)&W2[lp * 16 + 12];
  float p20 = r[0] * wA.x + r[1] * wA.z + r[2] * wB.x + r[3] * wB.z
            + r[4] * wC.x + r[5] * wC.z + r[6] * wD.x + r[7] * wD.z;
  float p21 = r[0] * wA.y + r[1] * wA.w + r[2] * wB.y + r[3] * wB.w
            + r[4] * wC.y + r[5] * wC.w + r[6] * wD.y + r[7] * wD.w;
#pragma unroll
  for (int o = 1; o <= 8; o <<= 1) { p20 += __shfl_xor(p20, o); p21 += __shfl_xor(p21, o); }
  if (lane == 0) {
    float4 v;
    v.x = p20; v.y = p21;
    v.z = p20 * as2[0] + p21 * as2[1];
    v.w = p20 * ad2[0] + p21 * ad2[1];
    nd[n] = v;
  }
}

// ---------- layer2 aggregation: 4 nodes/wave (16-lane granules) ----------
// Padded segments: pad packets have ez=-1e30 -> exp() = 0, safe to process.
__global__ __launch_bounds__(256) void k_agg2(const int* __restrict__ rowptr,
                                              const float4* __restrict__ cpk,
                                              const float4* __restrict__ nd,
                                              const float* __restrict__ b2,
                                              float* __restrict__ out) {
  int wid = (int)((blockIdx.x * 256 + threadIdx.x) >> 6);
  int lane = threadIdx.x & 63;
  int g = lane >> 4, lp = lane & 15;
  int n = wid * 4 + g;
  if (n >= NN) return;
  int s0 = rowptr[n], s1 = rowptr[n + 1];
  float adn = nd[n].w;
  float den = 0.f, acc0 = 0.f, acc1 = 0.f;
  for (int i = s0 + lp; i < s1; i += 16) {
    float4 pk = cpk[i];
    int s = __float_as_int(pk.z);
    float4 ns = nd[s];
    float v = ns.z + adn + pk.w;
    v = v > 0.f ? v : NEG_SLOPE * v;
    float p = __expf(v);
    den += p;
    acc0 += p * ns.x;
    acc1 += p * ns.y;
  }
#pragma unroll
  for (int o = 1; o <= 8; o <<= 1) {
    den += __shfl_xor(den, o);
    acc0 += __shfl_xor(acc0, o);
    acc1 += __shfl_xor(acc1, o);
  }
  if (lp == 0) {
    float2 r;
    r.x = acc0 / (den + GEPS) + b2[0];
    r.y = acc1 / (den + GEPS) + b2[1];
    *(float2*)&out[n * 2] = r;
  }
}

extern "C" void kernel_launch(void* const* d_in, const int* in_sizes, int n_in,
                              void* d_out, int out_size, void* d_ws, size_t ws_size,
                              hipStream_t stream) {
  (void)in_sizes; (void)n_in; (void)out_size; (void)ws_size;
  const float* x   = (const float*)d_in[0];
  const int*   ei  = (const int*)d_in[1];
  const float* ef  = (const float*)d_in[2];
  const float* W1  = (const float*)d_in[3];
  const float* We1 = (const float*)d_in[4];
  const float* as1 = (const float*)d_in[5];
  const float* ad1 = (const float*)d_in[6];
  const float* ae1 = (const float*)d_in[7];
  const float* b1  = (const float*)d_in[8];
  const float* W2  = (const float*)d_in[9];
  const float* We2 = (const float*)d_in[10];
  const float* as2 = (const float*)d_in[11];
  const float* ad2 = (const float*)d_in[12];
  const float* ae2 = (const float*)d_in[13];
  const float* b2  = (const float*)d_in[14];
  float* out = (float*)d_out;

  char* w = (char*)d_ws;
  auto alloc = [&](size_t bytes) -> char* {
    char* p = w; w += (bytes + 255) & ~(size_t)255; return p;
  };
  unsigned short* h1b = (unsigned short*)alloc((size_t)NN * 128 * 2);  // 25.6 MB
  float*  a1s    = (float*)alloc((size_t)NN * 2 * 4);
  float*  a1d    = (float*)alloc((size_t)NN * 2 * 4);
  float4* nd     = (float4*)alloc((size_t)NN * 16);
  float*  q      = (float*)alloc(64);
  float4* pq     = (float4*)alloc(128 * 16);
  int*    deg    = (int*)alloc((size_t)NN * 4);
  int*    rowptr = (int*)alloc((size_t)(NN + 1) * 4);
  int*    rank   = (int*)alloc((size_t)NE * 4);           // 6.4 MB
  int*    bsum   = (int*)alloc(128 * 4);
  float4* cpk    = (float4*)alloc(((size_t)NE + 8 * NN) * 16);  // padded CSR, 38.4 MB

  const int NB_SCAN = (NN + 1023) / 1024;                 // 98

  hipLaunchKernelGGL(k_prep, dim3(1), dim3(128), 0, stream,
                     We1, ae1, We2, ae2, W1, as1, ad1, q, pq);
  hipLaunchKernelGGL(k_gemm, dim3((NN + 127) / 128), dim3(512), 0, stream,
                     x, W1, pq, h1b, a1s, a1d);
  hipMemsetAsync(deg, 0, (size_t)NN * 4, stream);
  hipLaunchKernelGGL(k_hist, dim3((NE / 4 + 255) / 256), dim3(256), 0, stream, ei, deg, rank);
  hipLaunchKernelGGL(k_scan1, dim3(NB_SCAN), dim3(256), 0, stream, deg, bsum);
  hipLaunchKernelGGL(k_scan2, dim3(1), dim3(128), 0, stream, bsum, NB_SCAN);
  hipLaunchKernelGGL(k_scan3, dim3(NB_SCAN), dim3(256), 0, stream,
                     deg, bsum, a1s, a1d, rowptr, cpk);
  hipLaunchKernelGGL(k_scatter, dim3((NE / 4 + 255) / 256), dim3(256), 0, stream,
                     ei, ef, a1s, a1d, q, rowptr, rank, cpk);
  hipLaunchKernelGGL(k_agg1, dim3((NN * 64 + 255) / 256), dim3(256), 0, stream,
                     h1b, rowptr, cpk, b1, W2, as2, ad2, nd);
  hipLaunchKernelGGL(k_agg2, dim3(((NN + 3) / 4 * 64 + 255) / 256), dim3(256), 0, stream,
                     rowptr, cpk, nd, b2, out);
}

// Round 10
// 386.290 us; speedup vs baseline: 1.5550x; 1.0047x over previous
//
#include <hip/hip_runtime.h>
#include <hip/hip_bf16.h>

#define NN 100000
#define NE 1600000
#define NEG_SLOPE 0.2f
#define GEPS 1e-16f
#define WSHIFT 4.0f   // global exp shift: w = exp(alpha-4), softmax-invariant, keeps f16 in range

typedef __attribute__((ext_vector_type(8))) short short8;
typedef __attribute__((ext_vector_type(4))) float f32x4;
typedef __attribute__((ext_vector_type(2))) _Float16 h2v;

// fp32 -> bf16 round-to-nearest-even (MFMA staging only)
__device__ __forceinline__ unsigned short f2b(float f) {
  unsigned u = __float_as_uint(f);
  u += 0x7fffu + ((u >> 16) & 1u);
  return (unsigned short)(u >> 16);
}
// fp32 -> f16 (h1 storage: f16 has 11-bit mantissa, better than bf16 for |h|<8)
__device__ __forceinline__ unsigned short f2h(float f) {
  _Float16 h = (_Float16)f;
  return __builtin_bit_cast(unsigned short, h);
}
// pack two fp32 into f16x2 (lo, hi)
__device__ __forceinline__ unsigned pkh2(float lo, float hi) {
  return (unsigned)f2h(lo) | ((unsigned)f2h(hi) << 16);
}
__device__ __forceinline__ float dot2h(unsigned a, unsigned b, float c) {
  return __builtin_amdgcn_fdot2(__builtin_bit_cast(h2v, a), __builtin_bit_cast(h2v, b), c, false);
}
__device__ __forceinline__ unsigned permb(unsigned s0, unsigned s1, int sel) {
  return __builtin_amdgcn_perm(s0, s1, sel);
}
#define HSEL_LO 0x05040100   // (s1.lo16, s0.lo16)
#define HSEL_HI 0x07060302   // (s1.hi16, s0.hi16)
#define ONE2    0x3C003C00u  // f16 (1.0, 1.0)

// ---------- prep: q (edge-att vectors) + pq[k] = (W1@as1, W1@ad1) per head ----------
__global__ void k_prep(const float* __restrict__ We1, const float* __restrict__ ae1,
                       const float* __restrict__ We2, const float* __restrict__ ae2,
                       const float* __restrict__ W1, const float* __restrict__ as1,
                       const float* __restrict__ ad1,
                       float* __restrict__ q, float4* __restrict__ pq) {
  int t = threadIdx.x;
  if (t < 6) {
    int d = t >> 1, hh = t & 1;
    float s = 0.f;
    for (int c = 0; c < 64; ++c) s += We1[d * 128 + hh * 64 + c] * ae1[hh * 64 + c];
    q[t] = s;
  } else if (t < 9) {
    int d = t - 6;
    q[8 + d] = We2[d * 2 + 0] * ae2[0] + We2[d * 2 + 1] * ae2[1];
  }
  if (t < 128) {
    float s0 = 0.f, s1 = 0.f, d0 = 0.f, d1 = 0.f;
    for (int c = 0; c < 64; ++c) {
      float w0 = W1[t * 128 + c], w1 = W1[t * 128 + 64 + c];
      s0 += w0 * as1[c];      s1 += w1 * as1[64 + c];
      d0 += w0 * ad1[c];      d1 += w1 * ad1[64 + c];
    }
    pq[t] = make_float4(s0, s1, d0, d1);
  }
}

// ---------- layer1 GEMM via bf16 MFMA + fused attn scalars from fp32 x ----------
// Output h1b stored as f16 (not bf16): same MFMA, more precise storage.
__global__ __launch_bounds__(512, 4) void k_gemm(const float* __restrict__ x,
                                                 const float* __restrict__ W,
                                                 const float4* __restrict__ pq,
                                                 unsigned short* __restrict__ h1b,
                                                 float* __restrict__ a1s,
                                                 float* __restrict__ a1d) {
  __shared__ unsigned short xa[128 * 128];
  __shared__ unsigned short wt[128 * 128];
  int t = threadIdx.x;
  int row0 = blockIdx.x * 128;

  // stage W^T (fp32 -> bf16, transposed, swizzled)
  {
    int kr = t >> 2, n0 = (t & 3) * 32;
    const float* wp = &W[kr * 128 + n0];
    int cb = kr >> 3, klo = kr & 7;
#pragma unroll
    for (int j = 0; j < 8; ++j) {
      float4 v = *(const float4*)&wp[j * 4];
      int n = n0 + j * 4;
      wt[(n + 0) * 128 + ((cb ^ ((n + 0) & 15)) * 8) + klo] = f2b(v.x);
      wt[(n + 1) * 128 + ((cb ^ ((n + 1) & 15)) * 8) + klo] = f2b(v.y);
      wt[(n + 2) * 128 + ((cb ^ ((n + 2) & 15)) * 8) + klo] = f2b(v.z);
      wt[(n + 3) * 128 + ((cb ^ ((n + 3) & 15)) * 8) + klo] = f2b(v.w);
    }
  }
  // stage x tile (fp32 -> bf16, swizzled) + alpha-scalar partial dots on fp32 x
  {
    int lrow = t >> 2, qq = t & 3;
    int grow = row0 + lrow; if (grow >= NN) grow = NN - 1;
    const float* xp = &x[(size_t)grow * 128 + qq * 32];
    const float4* pqp = &pq[qq * 32];
    float ps0 = 0.f, ps1 = 0.f, pd0 = 0.f, pd1 = 0.f;
    int sw = lrow & 15;
#pragma unroll
    for (int j = 0; j < 4; ++j) {
      float4 u = *(const float4*)&xp[j * 8];
      float4 v = *(const float4*)&xp[j * 8 + 4];
      float xs[8] = {u.x, u.y, u.z, u.w, v.x, v.y, v.z, v.w};
      short8 sv;
#pragma unroll
      for (int e = 0; e < 8; ++e) {
        float4 pv = pqp[j * 8 + e];
        ps0 += xs[e] * pv.x; ps1 += xs[e] * pv.y;
        pd0 += xs[e] * pv.z; pd1 += xs[e] * pv.w;
        sv[e] = (short)f2b(xs[e]);
      }
      int c = qq * 4 + j;
      *(short8*)&xa[lrow * 128 + ((c ^ sw) * 8)] = sv;
    }
    ps0 += __shfl_xor(ps0, 1); ps0 += __shfl_xor(ps0, 2);
    ps1 += __shfl_xor(ps1, 1); ps1 += __shfl_xor(ps1, 2);
    pd0 += __shfl_xor(pd0, 1); pd0 += __shfl_xor(pd0, 2);
    pd1 += __shfl_xor(pd1, 1); pd1 += __shfl_xor(pd1, 2);
    if (qq == 0) {
      *(float2*)&a1s[grow * 2] = make_float2(ps0, ps1);
      *(float2*)&a1d[grow * 2] = make_float2(pd0, pd1);
    }
  }
  __syncthreads();

  int lane = t & 63, w = t >> 6;
  int m = lane & 15, quad = lane >> 4;
  int wm = (w & 1) * 64, wn = (w >> 1) * 32;
  f32x4 acc[4][2];
#pragma unroll
  for (int mi = 0; mi < 4; ++mi)
#pragma unroll
    for (int ni = 0; ni < 2; ++ni) acc[mi][ni] = (f32x4)(0.f);

#pragma unroll
  for (int kk = 0; kk < 4; ++kk) {
    int c = kk * 4 + quad;
    int co = (c ^ m) * 8;
    short8 a[4], b[2];
#pragma unroll
    for (int mi = 0; mi < 4; ++mi)
      a[mi] = *(const short8*)&xa[(wm + mi * 16 + m) * 128 + co];
#pragma unroll
    for (int ni = 0; ni < 2; ++ni)
      b[ni] = *(const short8*)&wt[(wn + ni * 16 + m) * 128 + co];
#pragma unroll
    for (int mi = 0; mi < 4; ++mi)
#pragma unroll
      for (int ni = 0; ni < 2; ++ni)
        acc[mi][ni] = __builtin_amdgcn_mfma_f32_16x16x32_bf16(a[mi], b[ni], acc[mi][ni], 0, 0, 0);
  }
#pragma unroll
  for (int mi = 0; mi < 4; ++mi)
#pragma unroll
    for (int r = 0; r < 4; ++r) {
      int grow = row0 + wm + mi * 16 + quad * 4 + r;
      if (grow >= NN) grow = NN - 1;
#pragma unroll
      for (int ni = 0; ni < 2; ++ni)
        h1b[(size_t)grow * 128 + wn + ni * 16 + m] = f2h(acc[mi][ni][r]);
    }
}

// ---------- CSR build: histogram + per-edge rank (the ONLY atomic pass) ----------
__global__ void k_hist(const int* __restrict__ ei, int* __restrict__ deg,
                       int* __restrict__ rank) {
  int t4 = blockIdx.x * 256 + threadIdx.x;
  if (t4 >= NE / 4) return;
  int4 d = *(const int4*)&ei[NE + t4 * 4];
  int4 rk;
  rk.x = atomicAdd(&deg[d.x], 1);
  rk.y = atomicAdd(&deg[d.y], 1);
  rk.z = atomicAdd(&deg[d.z], 1);
  rk.w = atomicAdd(&deg[d.w], 1);
  *(int4*)&rank[t4 * 4] = rk;
}

// padded segment length: (deg+1) rounded up to multiple of 8
__device__ __forceinline__ int padlen(int d) { return (d + 8) & ~7; }

__global__ void k_scan1(const int* __restrict__ deg, int* __restrict__ bsum) {
  __shared__ int lds[256];
  int t = threadIdx.x;
  int base = blockIdx.x * 1024 + t * 4;
  int s = 0;
  for (int j = 0; j < 4; ++j) { int i = base + j; s += (i < NN) ? padlen(deg[i]) : 0; }
  lds[t] = s; __syncthreads();
  for (int o = 128; o > 0; o >>= 1) { if (t < o) lds[t] += lds[t + o]; __syncthreads(); }
  if (t == 0) bsum[blockIdx.x] = lds[0];
}

__global__ void k_scan2(int* __restrict__ bsum, int nb) {
  __shared__ int lds[128];
  int t = threadIdx.x;
  int v = (t < nb) ? bsum[t] : 0;
  lds[t] = v; __syncthreads();
  for (int o = 1; o < 128; o <<= 1) {
    int u = (t >= o) ? lds[t - o] : 0;
    __syncthreads();
    lds[t] += u;
    __syncthreads();
  }
  if (t < nb) bsum[t] = lds[t] - v;   // exclusive
}

// scan3: rowptr (padded), self-loop packet at slot 0, zero-weight pad packets at tail.
// Packet layout: .x = f16x2 (w0,w1) = exp(alpha-4), .y = ez, .z = src, .w = 0.
// Pad packet: w01 = 0 (agg1 adds zero), ez = -1e30 -> agg2 exp = 0.
__global__ void k_scan3(const int* __restrict__ deg, const int* __restrict__ bbase,
                        const float* __restrict__ a1s, const float* __restrict__ a1d,
                        int* __restrict__ rowptr, float4* __restrict__ cpk) {
  __shared__ int lds[256];
  int t = threadIdx.x;
  int base = blockIdx.x * 1024 + t * 4;
  int v[4]; int s = 0;
  for (int j = 0; j < 4; ++j) { int i = base + j; v[j] = (i < NN) ? padlen(deg[i]) : 0; s += v[j]; }
  lds[t] = s; __syncthreads();
  for (int o = 1; o < 256; o <<= 1) {
    int u = (t >= o) ? lds[t - o] : 0;
    __syncthreads();
    lds[t] += u;
    __syncthreads();
  }
  int excl = lds[t] - s + bbase[blockIdx.x];
  for (int j = 0; j < 4; ++j) {
    int i = base + j;
    if (i <= NN) rowptr[i] = excl;
    if (i < NN) {
      float al0 = a1s[i * 2] + a1d[i * 2];
      float al1 = a1s[i * 2 + 1] + a1d[i * 2 + 1];
      al0 = al0 > 0.f ? al0 : NEG_SLOPE * al0;
      al1 = al1 > 0.f ? al1 : NEG_SLOPE * al1;
      float4 pk;
      pk.x = __uint_as_float(pkh2(__expf(al0 - WSHIFT), __expf(al1 - WSHIFT)));
      pk.y = 0.f; pk.z = __int_as_float(i); pk.w = 0.f;
      cpk[excl] = pk;                       // self-loop at slot 0
      float4 pad;
      pad.x = 0.f; pad.y = -1e30f; pad.z = __int_as_float(i); pad.w = 0.f;
      for (int k = 1 + deg[i]; k < v[j]; ++k) cpk[excl + k] = pad;
    }
    excl += v[j];
  }
}

// ---------- scatter edges into CSR: NO atomics (pos = rowptr[dst]+1+rank[e]) ----------
__global__ void k_scatter(const int* __restrict__ ei, const float* __restrict__ ef,
                          const float* __restrict__ a1s, const float* __restrict__ a1d,
                          const float* __restrict__ q, const int* __restrict__ rowptr,
                          const int* __restrict__ rank, float4* __restrict__ cpk) {
  int t4 = blockIdx.x * 256 + threadIdx.x;
  if (t4 >= NE / 4) return;
  int e0 = t4 * 4;
  int4 ss = *(const int4*)&ei[e0];
  int4 dd = *(const int4*)&ei[NE + e0];
  int4 rk = *(const int4*)&rank[e0];
  float4 fA = *(const float4*)&ef[e0 * 3];
  float4 fB = *(const float4*)&ef[e0 * 3 + 4];
  float4 fC = *(const float4*)&ef[e0 * 3 + 8];
  float f[4][3] = {{fA.x, fA.y, fA.z}, {fA.w, fB.x, fB.y},
                   {fB.z, fB.w, fC.x}, {fC.y, fC.z, fC.w}};
  int src[4] = {ss.x, ss.y, ss.z, ss.w};
  int dst[4] = {dd.x, dd.y, dd.z, dd.w};
  int rnk[4] = {rk.x, rk.y, rk.z, rk.w};
#pragma unroll
  for (int j = 0; j < 4; ++j) {
    float e0h = f[j][0] * q[0] + f[j][1] * q[2] + f[j][2] * q[4];
    float e1h = f[j][0] * q[1] + f[j][1] * q[3] + f[j][2] * q[5];
    float ez  = f[j][0] * q[8] + f[j][1] * q[9] + f[j][2] * q[10];
    float al0 = a1s[src[j] * 2] + a1d[dst[j] * 2] + e0h;
    float al1 = a1s[src[j] * 2 + 1] + a1d[dst[j] * 2 + 1] + e1h;
    al0 = al0 > 0.f ? al0 : NEG_SLOPE * al0;
    al1 = al1 > 0.f ? al1 : NEG_SLOPE * al1;
    int pos = rowptr[dst[j]] + 1 + rnk[j];
    float4 pk;
    pk.x = __uint_as_float(pkh2(__expf(al0 - WSHIFT), __expf(al1 - WSHIFT)));
    pk.y = ez; pk.z = __int_as_float(src[j]); pk.w = 0.f;
    cpk[pos] = pk;
  }
}

// ---------- layer1 aggregation + bias + ELU + layer2 projection epilogue ----------
// one wave per dst node; 16-lane granules; f16 h1 rows + f16x2 packed weights.
// Inner accumulation via v_perm channel-pairing + v_dot2_f32_f16 over edge pairs:
// 1 instr per (channel, edge-pair) instead of unpack+fma per (channel, edge).
__global__ __launch_bounds__(256) void k_agg1(const unsigned short* __restrict__ h1b,
                                              const int* __restrict__ rowptr,
                                              const float4* __restrict__ cpk,
                                              const float* __restrict__ b1,
                                              const float* __restrict__ W2,
                                              const float* __restrict__ as2,
                                              const float* __restrict__ ad2,
                                              float4* __restrict__ nd) {
  int n = (int)((blockIdx.x * 256 + threadIdx.x) >> 6);
  int lane = threadIdx.x & 63;
  if (n >= NN) return;
  int s0 = rowptr[n], s1 = rowptr[n + 1];
  int g = lane >> 4;
  int lp = lane & 15;
  int wsel = (lp >= 8) ? HSEL_HI : HSEL_LO;   // head select folded into weight perm

  float acc[8];
#pragma unroll
  for (int j = 0; j < 8; ++j) acc[j] = 0.f;
  float den = 0.f;

  int i = s0;
  for (; i + 16 <= s1; i += 16) {
    float4 pA = cpk[i + g], pB = cpk[i + 4 + g], pC = cpk[i + 8 + g], pD = cpk[i + 12 + g];
    uint4 vA = *((const uint4*)(h1b + ((size_t)__float_as_int(pA.z) << 7)) + lp);
    uint4 vB = *((const uint4*)(h1b + ((size_t)__float_as_int(pB.z) << 7)) + lp);
    uint4 vC = *((const uint4*)(h1b + ((size_t)__float_as_int(pC.z) << 7)) + lp);
    uint4 vD = *((const uint4*)(h1b + ((size_t)__float_as_int(pD.z) << 7)) + lp);
    unsigned wAB = permb(__float_as_uint(pB.x), __float_as_uint(pA.x), wsel);
    unsigned wCD = permb(__float_as_uint(pD.x), __float_as_uint(pC.x), wsel);
    den = dot2h(wAB, ONE2, den);
    den = dot2h(wCD, ONE2, den);
    acc[0] = dot2h(permb(vB.x, vA.x, HSEL_LO), wAB, acc[0]);
    acc[1] = dot2h(permb(vB.x, vA.x, HSEL_HI), wAB, acc[1]);
    acc[2] = dot2h(permb(vB.y, vA.y, HSEL_LO), wAB, acc[2]);
    acc[3] = dot2h(permb(vB.y, vA.y, HSEL_HI), wAB, acc[3]);
    acc[4] = dot2h(permb(vB.z, vA.z, HSEL_LO), wAB, acc[4]);
    acc[5] = dot2h(permb(vB.z, vA.z, HSEL_HI), wAB, acc[5]);
    acc[6] = dot2h(permb(vB.w, vA.w, HSEL_LO), wAB, acc[6]);
    acc[7] = dot2h(permb(vB.w, vA.w, HSEL_HI), wAB, acc[7]);
    acc[0] = dot2h(permb(vD.x, vC.x, HSEL_LO), wCD, acc[0]);
    acc[1] = dot2h(permb(vD.x, vC.x, HSEL_HI), wCD, acc[1]);
    acc[2] = dot2h(permb(vD.y, vC.y, HSEL_LO), wCD, acc[2]);
    acc[3] = dot2h(permb(vD.y, vC.y, HSEL_HI), wCD, acc[3]);
    acc[4] = dot2h(permb(vD.z, vC.z, HSEL_LO), wCD, acc[4]);
    acc[5] = dot2h(permb(vD.z, vC.z, HSEL_HI), wCD, acc[5]);
    acc[6] = dot2h(permb(vD.w, vC.w, HSEL_LO), wCD, acc[6]);
    acc[7] = dot2h(permb(vD.w, vC.w, HSEL_HI), wCD, acc[7]);
  }
  if (i < s1) {                       // exactly one 8-edge block
    float4 pA = cpk[i + g], pB = cpk[i + 4 + g];
    uint4 vA = *((const uint4*)(h1b + ((size_t)__float_as_int(pA.z) << 7)) + lp);
    uint4 vB = *((const uint4*)(h1b + ((size_t)__float_as_int(pB.z) << 7)) + lp);
    unsigned wAB = permb(__float_as_uint(pB.x), __float_as_uint(pA.x), wsel);
    den = dot2h(wAB, ONE2, den);
    acc[0] = dot2h(permb(vB.x, vA.x, HSEL_LO), wAB, acc[0]);
    acc[1] = dot2h(permb(vB.x, vA.x, HSEL_HI), wAB, acc[1]);
    acc[2] = dot2h(permb(vB.y, vA.y, HSEL_LO), wAB, acc[2]);
    acc[3] = dot2h(permb(vB.y, vA.y, HSEL_HI), wAB, acc[3]);
    acc[4] = dot2h(permb(vB.z, vA.z, HSEL_LO), wAB, acc[4]);
    acc[5] = dot2h(permb(vB.z, vA.z, HSEL_HI), wAB, acc[5]);
    acc[6] = dot2h(permb(vB.w, vA.w, HSEL_LO), wAB, acc[6]);
    acc[7] = dot2h(permb(vB.w, vA.w, HSEL_HI), wAB, acc[7]);
  }
#pragma unroll
  for (int o = 16; o <= 32; o <<= 1) {
    den += __shfl_xor(den, o);
#pragma unroll
    for (int j = 0; j < 8; ++j) acc[j] += __shfl_xor(acc[j], o);
  }
  float4 bA = *(const float4*)&b1[lp * 8];
  float4 bB = *(const float4*)&b1[lp * 8 + 4];
  float bb[8] = {bA.x, bA.y, bA.z, bA.w, bB.x, bB.y, bB.z, bB.w};
  float inv = 1.f / (den + GEPS);
  float r[8];
#pragma unroll
  for (int j = 0; j < 8; ++j) {
    float v = acc[j] * inv + bb[j];
    r[j] = v > 0.f ? v : __expf(v) - 1.f;   // ELU
  }
  float4 wA = *(const float4*)&W2[lp * 16];
  float4 wB = *(const float4*)&W2[lp * 16 + 4];
  float4 wC = *(const float4*)&W2[lp * 16 + 8];
  float4 wD = *(const float4*)&W2[lp * 16 + 12];
  float p20 = r[0] * wA.x + r[1] * wA.z + r[2] * wB.x + r[3] * wB.z
            + r[4] * wC.x + r[5] * wC.z + r[6] * wD.x + r[7] * wD.z;
  float p21 = r[0] * wA.y + r[1] * wA.w + r[2] * wB.y + r[3] * wB.w
            + r[4] * wC.y + r[5] * wC.w + r[6] * wD.y + r[7] * wD.w;
#pragma unroll
  for (int o = 1; o <= 8; o <<= 1) { p20 += __shfl_xor(p20, o); p21 += __shfl_xor(p21, o); }
  if (lane == 0) {
    float4 v;
    v.x = p20; v.y = p21;
    v.z = p20 * as2[0] + p21 * as2[1];
    v.w = p20 * ad2[0] + p21 * ad2[1];
    nd[n] = v;
  }
}

// ---------- layer2 aggregation: 4 nodes/wave (16-lane granules) ----------
// Pad packets: ez=-1e30 -> exp() = 0, safe to process.
__global__ __launch_bounds__(256) void k_agg2(const int* __restrict__ rowptr,
                                              const float4* __restrict__ cpk,
                                              const float4* __restrict__ nd,
                                              const float* __restrict__ b2,
                                              float* __restrict__ out) {
  int wid = (int)((blockIdx.x * 256 + threadIdx.x) >> 6);
  int lane = threadIdx.x & 63;
  int g = lane >> 4, lp = lane & 15;
  int n = wid * 4 + g;
  if (n >= NN) return;
  int s0 = rowptr[n], s1 = rowptr[n + 1];
  float adn = nd[n].w;
  float den = 0.f, acc0 = 0.f, acc1 = 0.f;
  for (int i = s0 + lp; i < s1; i += 16) {
    float4 pk = cpk[i];
    int s = __float_as_int(pk.z);
    float4 ns = nd[s];
    float v = ns.z + adn + pk.y;
    v = v > 0.f ? v : NEG_SLOPE * v;
    float p = __expf(v);
    den += p;
    acc0 += p * ns.x;
    acc1 += p * ns.y;
  }
#pragma unroll
  for (int o = 1; o <= 8; o <<= 1) {
    den += __shfl_xor(den, o);
    acc0 += __shfl_xor(acc0, o);
    acc1 += __shfl_xor(acc1, o);
  }
  if (lp == 0) {
    float2 r;
    r.x = acc0 / (den + GEPS) + b2[0];
    r.y = acc1 / (den + GEPS) + b2[1];
    *(float2*)&out[n * 2] = r;
  }
}

extern "C" void kernel_launch(void* const* d_in, const int* in_sizes, int n_in,
                              void* d_out, int out_size, void* d_ws, size_t ws_size,
                              hipStream_t stream) {
  (void)in_sizes; (void)n_in; (void)out_size; (void)ws_size;
  const float* x   = (const float*)d_in[0];
  const int*   ei  = (const int*)d_in[1];
  const float* ef  = (const float*)d_in[2];
  const float* W1  = (const float*)d_in[3];
  const float* We1 = (const float*)d_in[4];
  const float* as1 = (const float*)d_in[5];
  const float* ad1 = (const float*)d_in[6];
  const float* ae1 = (const float*)d_in[7];
  const float* b1  = (const float*)d_in[8];
  const float* W2  = (const float*)d_in[9];
  const float* We2 = (const float*)d_in[10];
  const float* as2 = (const float*)d_in[11];
  const float* ad2 = (const float*)d_in[12];
  const float* ae2 = (const float*)d_in[13];
  const float* b2  = (const float*)d_in[14];
  float* out = (float*)d_out;

  char* w = (char*)d_ws;
  auto alloc = [&](size_t bytes) -> char* {
    char* p = w; w += (bytes + 255) & ~(size_t)255; return p;
  };
  unsigned short* h1b = (unsigned short*)alloc((size_t)NN * 128 * 2);  // 25.6 MB (f16)
  float*  a1s    = (float*)alloc((size_t)NN * 2 * 4);
  float*  a1d    = (float*)alloc((size_t)NN * 2 * 4);
  float4* nd     = (float4*)alloc((size_t)NN * 16);
  float*  q      = (float*)alloc(64);
  float4* pq     = (float4*)alloc(128 * 16);
  int*    deg    = (int*)alloc((size_t)NN * 4);
  int*    rowptr = (int*)alloc((size_t)(NN + 1) * 4);
  int*    rank   = (int*)alloc((size_t)NE * 4);           // 6.4 MB
  int*    bsum   = (int*)alloc(128 * 4);
  float4* cpk    = (float4*)alloc(((size_t)NE + 8 * NN) * 16);  // padded CSR, 38.4 MB

  const int NB_SCAN = (NN + 1023) / 1024;                 // 98

  hipLaunchKernelGGL(k_prep, dim3(1), dim3(128), 0, stream,
                     We1, ae1, We2, ae2, W1, as1, ad1, q, pq);
  hipLaunchKernelGGL(k_gemm, dim3((NN + 127) / 128), dim3(512), 0, stream,
                     x, W1, pq, h1b, a1s, a1d);
  hipMemsetAsync(deg, 0, (size_t)NN * 4, stream);
  hipLaunchKernelGGL(k_hist, dim3((NE / 4 + 255) / 256), dim3(256), 0, stream, ei, deg, rank);
  hipLaunchKernelGGL(k_scan1, dim3(NB_SCAN), dim3(256), 0, stream, deg, bsum);
  hipLaunchKernelGGL(k_scan2, dim3(1), dim3(128), 0, stream, bsum, NB_SCAN);
  hipLaunchKernelGGL(k_scan3, dim3(NB_SCAN), dim3(256), 0, stream,
                     deg, bsum, a1s, a1d, rowptr, cpk);
  hipLaunchKernelGGL(k_scatter, dim3((NE / 4 + 255) / 256), dim3(256), 0, stream,
                     ei, ef, a1s, a1d, q, rowptr, rank, cpk);
  hipLaunchKernelGGL(k_agg1, dim3((NN * 64 + 255) / 256), dim3(256), 0, stream,
                     h1b, rowptr, cpk, b1, W2, as2, ad2, nd);
  hipLaunchKernelGGL(k_agg2, dim3(((NN + 3) / 4 * 64 + 255) / 256), dim3(256), 0, stream,
                     rowptr, cpk, nd, b2, out);
}